// Round 1
// baseline (776.949 us; speedup 1.0000x reference)
//
#include <hip/hip_runtime.h>
#include <hip/hip_bf16.h>

// Problem dims (fixed)
#define B_ 2
#define L_ 2048
#define D_ 1024
#define E_ 2048
#define N_ 16
#define DR_ 64
#define DC_ 4
#define M_ (B_*L_)   // 4096 rows

typedef __attribute__((ext_vector_type(8))) short bf16x8;
typedef __attribute__((ext_vector_type(4))) float f32x4;

__device__ __forceinline__ ushort f2bf(float x){
    union { float f; unsigned u; } v; v.f = x;
    unsigned r = v.u + 0x7FFFu + ((v.u >> 16) & 1u);
    return (ushort)(r >> 16);
}
__device__ __forceinline__ float bf2f(ushort u){
    union { unsigned u; float f; } v; v.u = ((unsigned)u) << 16;
    return v.f;
}

// ---------------- convert f32 -> bf16 (vec4) ----------------
__global__ void cvt4_k(const float* __restrict__ in, ushort* __restrict__ out, int n4){
    int i = blockIdx.x * 256 + threadIdx.x;
    if (i < n4){
        float4 v = ((const float4*)in)[i];
        ushort4 o;
        o.x = f2bf(v.x); o.y = f2bf(v.y); o.z = f2bf(v.z); o.w = f2bf(v.w);
        ((ushort4*)out)[i] = o;
    }
}

__global__ void zero16_k(ushort* __restrict__ p, int n){
    int i = blockIdx.x * 256 + threadIdx.x;
    if (i < n) p[i] = 0;
}

// ---------------- RMSNorm -> bf16 ----------------
__global__ __launch_bounds__(256) void rmsnorm_k(const float* __restrict__ resid,
                                                 const float* __restrict__ norm_w,
                                                 ushort* __restrict__ xn){
    int row = blockIdx.x;
    const float4* r = (const float4*)(resid + (size_t)row * D_);
    float4 v = r[threadIdx.x];
    float ss = v.x*v.x + v.y*v.y + v.z*v.z + v.w*v.w;
    for (int m = 32; m; m >>= 1) ss += __shfl_xor(ss, m);
    __shared__ float sred[4];
    if ((threadIdx.x & 63) == 0) sred[threadIdx.x >> 6] = ss;
    __syncthreads();
    float tot = sred[0] + sred[1] + sred[2] + sred[3];
    float scale = rsqrtf(tot / (float)D_ + 1e-5f);
    const float4* wv = (const float4*)norm_w;
    float4 w = wv[threadIdx.x];
    ushort4 o;
    o.x = f2bf(v.x * scale * w.x);
    o.y = f2bf(v.y * scale * w.y);
    o.z = f2bf(v.z * scale * w.z);
    o.w = f2bf(v.w * scale * w.w);
    ((ushort4*)(xn + (size_t)row * D_))[threadIdx.x] = o;
}

// ---------------- GEMM: C[M,N] = A[M,K] * B[N,K]^T, bf16 in, f32 acc ----------------
// EPI: 0 = f32 store, 1 = bf16 store, 2 = softplus(acc + aux[col]) f32 store, 3 = acc + aux[idx] f32 store
#define BM 128
#define BN 128
#define BK 64
#define LDT 72

template<int EPI>
__global__ __launch_bounds__(256)
void gemm_bt(const ushort* __restrict__ A, const ushort* __restrict__ Bm,
             void* __restrict__ Cp, const float* __restrict__ aux,
             int M, int N, int K, int lda, int ldb, int ldc){
    __shared__ __align__(16) ushort As[BM * LDT];
    __shared__ __align__(16) ushort Bs[BN * LDT];
    const int col0 = blockIdx.x * BN;
    const int row0 = blockIdx.y * BM;
    const int tid = threadIdx.x;
    const int lane = tid & 63;
    const int wid = tid >> 6;
    const int wm = wid >> 1, wn = wid & 1;   // 2x2 waves of 64x64
    f32x4 acc[4][4] = {};

    const int lr = tid >> 3;         // 0..31 row within group
    const int lc = (tid & 7) * 8;    // 0..56 col (elements)

    for (int k0 = 0; k0 < K; k0 += BK){
        #pragma unroll
        for (int i = 0; i < 4; ++i){
            int r = lr + 32 * i;
            *(uint4*)(As + r * LDT + lc) =
                *(const uint4*)(A + (size_t)(row0 + r) * lda + k0 + lc);
            *(uint4*)(Bs + r * LDT + lc) =
                *(const uint4*)(Bm + (size_t)(col0 + r) * ldb + k0 + lc);
        }
        __syncthreads();
        #pragma unroll
        for (int kk = 0; kk < 2; ++kk){
            bf16x8 af[4], bfr[4];
            const int krow = lane & 15;
            const int kcol = kk * 32 + (lane >> 4) * 8;
            #pragma unroll
            for (int mi = 0; mi < 4; ++mi)
                af[mi] = *(const bf16x8*)(As + (wm*64 + mi*16 + krow) * LDT + kcol);
            #pragma unroll
            for (int ni = 0; ni < 4; ++ni)
                bfr[ni] = *(const bf16x8*)(Bs + (wn*64 + ni*16 + krow) * LDT + kcol);
            #pragma unroll
            for (int mi = 0; mi < 4; ++mi)
                #pragma unroll
                for (int ni = 0; ni < 4; ++ni)
                    acc[mi][ni] = __builtin_amdgcn_mfma_f32_16x16x32_bf16(af[mi], bfr[ni], acc[mi][ni], 0, 0, 0);
        }
        __syncthreads();
    }

    #pragma unroll
    for (int mi = 0; mi < 4; ++mi)
        #pragma unroll
        for (int ni = 0; ni < 4; ++ni)
            #pragma unroll
            for (int j = 0; j < 4; ++j){
                int r = row0 + wm*64 + mi*16 + (lane >> 4) * 4 + j;
                int c = col0 + wn*64 + ni*16 + (lane & 15);
                size_t idx = (size_t)r * ldc + c;
                float v = acc[mi][ni][j];
                if (EPI == 0){
                    ((float*)Cp)[idx] = v;
                } else if (EPI == 1){
                    ((ushort*)Cp)[idx] = f2bf(v);
                } else if (EPI == 2){
                    float z = v + aux[c];
                    ((float*)Cp)[idx] = (z > 20.f) ? z : log1pf(__expf(z));
                } else {
                    ((float*)Cp)[idx] = v + aux[idx];
                }
            }
}

// ---------------- causal depthwise conv1d + silu ----------------
__global__ __launch_bounds__(256) void conv_silu_k(const ushort* __restrict__ xpre,
                                                   const float* __restrict__ conv_w,
                                                   const float* __restrict__ conv_b,
                                                   float* __restrict__ xf,
                                                   ushort* __restrict__ xb){
    int idx = blockIdx.x * 256 + threadIdx.x;
    if (idx >= M_ * E_) return;
    int e = idx & (E_ - 1);
    int bl = idx >> 11;          // / E_
    int t = bl & (L_ - 1);
    float4 w = ((const float4*)conv_w)[e];
    float acc = conv_b[e];
    // out[t] = b + sum_k x[t-3+k] * w[k]
    if (t >= 3) acc += bf2f(xpre[idx - 3*E_]) * w.x;
    if (t >= 2) acc += bf2f(xpre[idx - 2*E_]) * w.y;
    if (t >= 1) acc += bf2f(xpre[idx - 1*E_]) * w.z;
    acc += bf2f(xpre[idx]) * w.w;
    float s = acc / (1.f + __expf(-acc));
    xf[idx] = s;
    xb[idx] = f2bf(s);
}

// ---------------- selective scan ----------------
// grid: (E_/16, B_), block 256 = 16 e x 16 n
__global__ __launch_bounds__(256) void scan_k(const float* __restrict__ delta,
                                              const float* __restrict__ xf,
                                              const ushort* __restrict__ C96,
                                              const float* __restrict__ A_log,
                                              float* __restrict__ ys){
    const int b = blockIdx.y;
    const int e0 = blockIdx.x * 16;
    const int n = threadIdx.x & 15;
    const int ei = threadIdx.x >> 4;
    const int e = e0 + ei;
    const float Aen = -__expf(A_log[e * N_ + n]);
    float h = 0.f;
    __shared__ float sd[64][16], sx[64][16], sB[64][16], sC[64][16], sy[64][16];

    for (int t0 = 0; t0 < L_; t0 += 64){
        #pragma unroll
        for (int i = 0; i < 4; ++i){
            int j = threadIdx.x + 256 * i;
            int t = j >> 4, col = j & 15;
            size_t rowbase = (size_t)(b * L_ + t0 + t);
            sd[t][col] = delta[rowbase * E_ + e0 + col];
            sx[t][col] = xf[rowbase * E_ + e0 + col];
            sB[t][col] = bf2f(C96[rowbase * 128 + 64 + col]);
            sC[t][col] = bf2f(C96[rowbase * 128 + 80 + col]);
        }
        __syncthreads();
        #pragma unroll 4
        for (int t = 0; t < 64; ++t){
            float dt = sd[t][ei];
            float xt = sx[t][ei];
            float bt = sB[t][n];
            float ct = sC[t][n];
            h = __expf(dt * Aen) * h + (dt * xt) * bt;
            float y = h * ct;
            y += __shfl_xor(y, 1);
            y += __shfl_xor(y, 2);
            y += __shfl_xor(y, 4);
            y += __shfl_xor(y, 8);
            if (n == 0) sy[t][ei] = y;
        }
        __syncthreads();
        #pragma unroll
        for (int i = 0; i < 4; ++i){
            int j = threadIdx.x + 256 * i;
            int t = j >> 4, col = j & 15;
            ys[(size_t)(b * L_ + t0 + t) * E_ + e0 + col] = sy[t][col];
        }
        __syncthreads();
    }
}

// ---------------- gating: y2 = (ys + W_D*x) * silu(skip) -> bf16 ----------------
__global__ __launch_bounds__(256) void gate_k(const float* __restrict__ ys,
                                              const float* __restrict__ xf,
                                              const ushort* __restrict__ skipb,
                                              const float* __restrict__ W_D,
                                              ushort* __restrict__ y2){
    int idx = blockIdx.x * 256 + threadIdx.x;
    if (idx >= M_ * E_) return;
    int e = idx & (E_ - 1);
    float sk = bf2f(skipb[idx]);
    float g = sk / (1.f + __expf(-sk));
    float y = ys[idx] + W_D[e] * xf[idx];
    y2[idx] = f2bf(y * g);
}

// ---------------- launch ----------------
extern "C" void kernel_launch(void* const* d_in, const int* in_sizes, int n_in,
                              void* d_out, int out_size, void* d_ws, size_t ws_size,
                              hipStream_t stream){
    const float* resid  = (const float*)d_in[0];
    const float* norm_w = (const float*)d_in[1];
    const float* skip_w = (const float*)d_in[2];
    const float* in_w   = (const float*)d_in[3];
    const float* conv_w = (const float*)d_in[4];
    const float* conv_b = (const float*)d_in[5];
    const float* wd1    = (const float*)d_in[6];
    const float* wd2    = (const float*)d_in[7];
    const float* wd2_b  = (const float*)d_in[8];
    const float* wB     = (const float*)d_in[9];
    const float* wC     = (const float*)d_in[10];
    const float* A_log  = (const float*)d_in[11];
    const float* W_D    = (const float*)d_in[12];
    const float* out_w  = (const float*)d_in[13];
    float* out = (float*)d_out;

    char* ws = (char*)d_ws;
    size_t off = 0;
    auto alloc = [&](size_t bytes) -> char* {
        char* p = ws + off;
        off += (bytes + 255) & ~(size_t)255;
        return p;
    };
    // --- aliased region: wi, wsk, xn, xpre are all dead before delta GEMM runs;
    //     delta (32MB f32) reuses their combined 32MB.
    char* alias_base = ws;
    ushort* wi_b    = (ushort*)alloc((size_t)E_ * D_ * 2);   // 4MB
    ushort* wsk_b   = (ushort*)alloc((size_t)E_ * D_ * 2);   // 4MB
    ushort* xn_b    = (ushort*)alloc((size_t)M_ * D_ * 2);   // 8MB
    ushort* xpre_b  = (ushort*)alloc((size_t)M_ * E_ * 2);   // 16MB
    float*  deltaf  = (float*)alias_base;                    // 32MB alias
    // --- persistent buffers
    ushort* wo_b    = (ushort*)alloc((size_t)D_ * E_ * 2);       // 4MB
    ushort* wd2_bf  = (ushort*)alloc((size_t)E_ * DR_ * 2);      // 256KB
    ushort* W96_b   = (ushort*)alloc((size_t)128 * E_ * 2);      // 512KB
    ushort* skip_b  = (ushort*)alloc((size_t)M_ * E_ * 2);       // 16MB
    float*  xff     = (float*)alloc((size_t)M_ * E_ * 4);        // 32MB
    ushort* xb_b    = (ushort*)alloc((size_t)M_ * E_ * 2);       // 16MB
    ushort* C96_b   = (ushort*)alloc((size_t)M_ * 128 * 2);      // 1MB
    float*  ysf     = (float*)alloc((size_t)M_ * E_ * 4);        // 32MB
    ushort* y2_b    = (ushort*)alloc((size_t)M_ * E_ * 2);       // 16MB
    (void)ws_size; (void)in_sizes; (void)n_in; (void)out_size;

    const int thr = 256;
    auto blocks4 = [](int n){ return (n/4 + 255) / 256; };

    // weight conversions
    cvt4_k<<<blocks4(E_*D_), thr, 0, stream>>>(in_w,   wi_b,   E_*D_/4);
    cvt4_k<<<blocks4(E_*D_), thr, 0, stream>>>(skip_w, wsk_b,  E_*D_/4);
    cvt4_k<<<blocks4(D_*E_), thr, 0, stream>>>(out_w,  wo_b,   D_*E_/4);
    cvt4_k<<<blocks4(E_*DR_), thr, 0, stream>>>(wd2,   wd2_bf, E_*DR_/4);
    cvt4_k<<<blocks4(DR_*E_), thr, 0, stream>>>(wd1,   W96_b,            DR_*E_/4);
    cvt4_k<<<blocks4(N_*E_),  thr, 0, stream>>>(wB,    W96_b + 64*E_,    N_*E_/4);
    cvt4_k<<<blocks4(N_*E_),  thr, 0, stream>>>(wC,    W96_b + 80*E_,    N_*E_/4);
    zero16_k<<<(32*E_ + 255)/256, thr, 0, stream>>>(W96_b + 96*E_, 32*E_);

    // RMSNorm
    rmsnorm_k<<<M_, thr, 0, stream>>>(resid, norm_w, xn_b);

    // in-proj and skip-proj GEMMs: [4096,2048] = [4096,1024] x [2048,1024]^T
    gemm_bt<1><<<dim3(E_/BN, M_/BM), thr, 0, stream>>>(xn_b, wi_b,  xpre_b, nullptr, M_, E_, D_, D_, D_, E_);
    gemm_bt<1><<<dim3(E_/BN, M_/BM), thr, 0, stream>>>(xn_b, wsk_b, skip_b, nullptr, M_, E_, D_, D_, D_, E_);

    // conv + silu
    conv_silu_k<<<(M_*E_ + 255)/256, thr, 0, stream>>>(xpre_b, conv_w, conv_b, xff, xb_b);

    // skinny GEMM: C96[4096,128] = x[4096,2048] x W96[128,2048]^T  (cols: 0..63 xr, 64..79 Bm, 80..95 Cm)
    gemm_bt<1><<<dim3(1, M_/BM), thr, 0, stream>>>(xb_b, W96_b, C96_b, nullptr, M_, 128, E_, E_, E_, 128);

    // delta GEMM: delta[4096,2048] = softplus(xr[4096,64] x wd2[2048,64]^T + wd2_b)
    gemm_bt<2><<<dim3(E_/BN, M_/BM), thr, 0, stream>>>(C96_b, wd2_bf, deltaf, wd2_b, M_, E_, DR_, 128, DR_, E_);

    // selective scan
    scan_k<<<dim3(E_/16, B_), thr, 0, stream>>>(deltaf, xff, C96_b, A_log, ysf);

    // gating
    gate_k<<<(M_*E_ + 255)/256, thr, 0, stream>>>(ysf, xff, skip_b, W_D, y2_b);

    // out-proj + residual: out[4096,1024] = y2[4096,2048] x out_w[1024,2048]^T + resid
    gemm_bt<3><<<dim3(D_/BN, M_/BM), thr, 0, stream>>>(y2_b, wo_b, out, resid, M_, D_, E_, E_, E_, D_);
}

// Round 2
// 719.328 us; speedup vs baseline: 1.0801x; 1.0801x over previous
//
#include <hip/hip_runtime.h>
#include <hip/hip_bf16.h>

// Problem dims (fixed)
#define B_ 2
#define L_ 2048
#define D_ 1024
#define E_ 2048
#define N_ 16
#define DR_ 64
#define DC_ 4
#define M_ (B_*L_)   // 4096 rows

typedef __attribute__((ext_vector_type(8))) short bf16x8;
typedef __attribute__((ext_vector_type(4))) float f32x4;

__device__ __forceinline__ ushort f2bf(float x){
    union { float f; unsigned u; } v; v.f = x;
    unsigned r = v.u + 0x7FFFu + ((v.u >> 16) & 1u);
    return (ushort)(r >> 16);
}
__device__ __forceinline__ float bf2f(ushort u){
    union { unsigned u; float f; } v; v.u = ((unsigned)u) << 16;
    return v.f;
}

// ---------------- convert f32 -> bf16 (vec4) ----------------
__global__ void cvt4_k(const float* __restrict__ in, ushort* __restrict__ out, int n4){
    int i = blockIdx.x * 256 + threadIdx.x;
    if (i < n4){
        float4 v = ((const float4*)in)[i];
        ushort4 o;
        o.x = f2bf(v.x); o.y = f2bf(v.y); o.z = f2bf(v.z); o.w = f2bf(v.w);
        ((ushort4*)out)[i] = o;
    }
}

__global__ void zero16_k(ushort* __restrict__ p, int n){
    int i = blockIdx.x * 256 + threadIdx.x;
    if (i < n) p[i] = 0;
}

// ---------------- RMSNorm -> bf16 ----------------
__global__ __launch_bounds__(256) void rmsnorm_k(const float* __restrict__ resid,
                                                 const float* __restrict__ norm_w,
                                                 ushort* __restrict__ xn){
    int row = blockIdx.x;
    const float4* r = (const float4*)(resid + (size_t)row * D_);
    float4 v = r[threadIdx.x];
    float ss = v.x*v.x + v.y*v.y + v.z*v.z + v.w*v.w;
    for (int m = 32; m; m >>= 1) ss += __shfl_xor(ss, m);
    __shared__ float sred[4];
    if ((threadIdx.x & 63) == 0) sred[threadIdx.x >> 6] = ss;
    __syncthreads();
    float tot = sred[0] + sred[1] + sred[2] + sred[3];
    float scale = rsqrtf(tot / (float)D_ + 1e-5f);
    const float4* wv = (const float4*)norm_w;
    float4 w = wv[threadIdx.x];
    ushort4 o;
    o.x = f2bf(v.x * scale * w.x);
    o.y = f2bf(v.y * scale * w.y);
    o.z = f2bf(v.z * scale * w.z);
    o.w = f2bf(v.w * scale * w.w);
    ((ushort4*)(xn + (size_t)row * D_))[threadIdx.x] = o;
}

// ---------------- GEMM: C[M,N] = A[M,K] * B[N,K]^T, bf16 in, f32 acc ----------------
// EPI: 0 = f32 store, 1 = bf16 store, 2 = softplus(acc + aux[col]) f32 store, 3 = acc + aux[idx] f32 store
#define BM 128
#define BN 128
#define BK 64
#define LDT 72

template<int EPI>
__global__ __launch_bounds__(256)
void gemm_bt(const ushort* __restrict__ A, const ushort* __restrict__ Bm,
             void* __restrict__ Cp, const float* __restrict__ aux,
             int M, int N, int K, int lda, int ldb, int ldc){
    __shared__ __align__(16) ushort As[BM * LDT];
    __shared__ __align__(16) ushort Bs[BN * LDT];
    const int col0 = blockIdx.x * BN;
    const int row0 = blockIdx.y * BM;
    const int tid = threadIdx.x;
    const int lane = tid & 63;
    const int wid = tid >> 6;
    const int wm = wid >> 1, wn = wid & 1;   // 2x2 waves of 64x64
    f32x4 acc[4][4] = {};

    const int lr = tid >> 3;         // 0..31 row within group
    const int lc = (tid & 7) * 8;    // 0..56 col (elements)

    for (int k0 = 0; k0 < K; k0 += BK){
        #pragma unroll
        for (int i = 0; i < 4; ++i){
            int r = lr + 32 * i;
            *(uint4*)(As + r * LDT + lc) =
                *(const uint4*)(A + (size_t)(row0 + r) * lda + k0 + lc);
            *(uint4*)(Bs + r * LDT + lc) =
                *(const uint4*)(Bm + (size_t)(col0 + r) * ldb + k0 + lc);
        }
        __syncthreads();
        #pragma unroll
        for (int kk = 0; kk < 2; ++kk){
            bf16x8 af[4], bfr[4];
            const int krow = lane & 15;
            const int kcol = kk * 32 + (lane >> 4) * 8;
            #pragma unroll
            for (int mi = 0; mi < 4; ++mi)
                af[mi] = *(const bf16x8*)(As + (wm*64 + mi*16 + krow) * LDT + kcol);
            #pragma unroll
            for (int ni = 0; ni < 4; ++ni)
                bfr[ni] = *(const bf16x8*)(Bs + (wn*64 + ni*16 + krow) * LDT + kcol);
            #pragma unroll
            for (int mi = 0; mi < 4; ++mi)
                #pragma unroll
                for (int ni = 0; ni < 4; ++ni)
                    acc[mi][ni] = __builtin_amdgcn_mfma_f32_16x16x32_bf16(af[mi], bfr[ni], acc[mi][ni], 0, 0, 0);
        }
        __syncthreads();
    }

    #pragma unroll
    for (int mi = 0; mi < 4; ++mi)
        #pragma unroll
        for (int ni = 0; ni < 4; ++ni)
            #pragma unroll
            for (int j = 0; j < 4; ++j){
                int r = row0 + wm*64 + mi*16 + (lane >> 4) * 4 + j;
                int c = col0 + wn*64 + ni*16 + (lane & 15);
                size_t idx = (size_t)r * ldc + c;
                float v = acc[mi][ni][j];
                if (EPI == 0){
                    ((float*)Cp)[idx] = v;
                } else if (EPI == 1){
                    ((ushort*)Cp)[idx] = f2bf(v);
                } else if (EPI == 2){
                    float z = v + aux[c];
                    ((float*)Cp)[idx] = (z > 20.f) ? z : log1pf(__expf(z));
                } else {
                    ((float*)Cp)[idx] = v + aux[idx];
                }
            }
}

// ---------------- causal depthwise conv1d + silu (vec4 along e) ----------------
__global__ __launch_bounds__(256) void conv_silu_k(const ushort* __restrict__ xpre,
                                                   const float* __restrict__ conv_w,
                                                   const float* __restrict__ conv_b,
                                                   float* __restrict__ xf,
                                                   ushort* __restrict__ xb){
    int i4 = blockIdx.x * 256 + threadIdx.x;       // index over groups of 4 elems
    if (i4 >= M_ * E_ / 4) return;
    int idx = i4 * 4;
    int e = idx & (E_ - 1);
    int bl = idx >> 11;
    int t = bl & (L_ - 1);
    float acc[4];
    #pragma unroll
    for (int j = 0; j < 4; ++j) acc[j] = conv_b[e + j];
    #pragma unroll
    for (int k = 0; k < 4; ++k){
        int dt = 3 - k;                            // tap k uses x[t - (3-k)], weight conv_w[e][k]
        if (t >= dt){
            ushort4 xv = *(const ushort4*)(xpre + idx - dt * E_);
            acc[0] += bf2f(xv.x) * conv_w[(e+0)*4 + k];
            acc[1] += bf2f(xv.y) * conv_w[(e+1)*4 + k];
            acc[2] += bf2f(xv.z) * conv_w[(e+2)*4 + k];
            acc[3] += bf2f(xv.w) * conv_w[(e+3)*4 + k];
        }
    }
    float4 so; ushort4 sb;
    float* sp = (float*)&so;
    #pragma unroll
    for (int j = 0; j < 4; ++j){
        float s = acc[j] / (1.f + __expf(-acc[j]));
        sp[j] = s;
    }
    sb.x = f2bf(so.x); sb.y = f2bf(so.y); sb.z = f2bf(so.z); sb.w = f2bf(so.w);
    *(float4*)(xf + idx) = so;
    *(ushort4*)(xb + idx) = sb;
}

// ---------------- selective scan (register-prefetch double-buffered) ----------------
// grid: (E_/16, B_), block 256 = 16 e x 16 n
#define SCHUNK 64
__global__ __launch_bounds__(256) void scan_k(const float* __restrict__ delta,
                                              const float* __restrict__ xf,
                                              const ushort* __restrict__ C96,
                                              const float* __restrict__ A_log,
                                              float* __restrict__ ys){
    const int b = blockIdx.y;
    const int e0 = blockIdx.x * 16;
    const int n = threadIdx.x & 15;
    const int ei = threadIdx.x >> 4;
    const int e = e0 + ei;
    const float Aen = -__expf(A_log[e * N_ + n]);
    float h = 0.f;
    __shared__ float sd[2][SCHUNK][16], sx[2][SCHUNK][16];
    __shared__ float sB[2][SCHUNK][16], sC[2][SCHUNK][16];
    __shared__ float sy[SCHUNK][16];

    // staging mapping: thread j covers (t = j>>2, cols qc..qc+3)
    const int tq = threadIdx.x >> 2;
    const int qc = (threadIdx.x & 3) * 4;

    float4 rd, rx;
    ushort4 rB, rC;

    auto issue = [&](int t0){
        size_t row = (size_t)(b * L_ + t0 + tq);
        rd = *(const float4*)(delta + row * E_ + e0 + qc);
        rx = *(const float4*)(xf    + row * E_ + e0 + qc);
        rB = *(const ushort4*)(C96 + row * 128 + 64 + qc);
        rC = *(const ushort4*)(C96 + row * 128 + 80 + qc);
    };
    auto commit = [&](int buf){
        *(float4*)&sd[buf][tq][qc] = rd;
        *(float4*)&sx[buf][tq][qc] = rx;
        sB[buf][tq][qc+0] = bf2f(rB.x); sB[buf][tq][qc+1] = bf2f(rB.y);
        sB[buf][tq][qc+2] = bf2f(rB.z); sB[buf][tq][qc+3] = bf2f(rB.w);
        sC[buf][tq][qc+0] = bf2f(rC.x); sC[buf][tq][qc+1] = bf2f(rC.y);
        sC[buf][tq][qc+2] = bf2f(rC.z); sC[buf][tq][qc+3] = bf2f(rC.w);
    };

    const int NCH = L_ / SCHUNK;
    issue(0);
    commit(0);
    if (NCH > 1) issue(SCHUNK);           // chunk 1 loads in flight during chunk 0 compute
    __syncthreads();

    for (int c = 0; c < NCH; ++c){
        const int buf = c & 1;
        #pragma unroll 4
        for (int t = 0; t < SCHUNK; ++t){
            float dt = sd[buf][t][ei];
            float xt = sx[buf][t][ei];
            float bt = sB[buf][t][n];
            float ct = sC[buf][t][n];
            h = __expf(dt * Aen) * h + (dt * xt) * bt;
            float y = h * ct;
            y += __shfl_xor(y, 1);
            y += __shfl_xor(y, 2);
            y += __shfl_xor(y, 4);
            y += __shfl_xor(y, 8);
            if (n == 0) sy[t][ei] = y;
        }
        __syncthreads();
        // store y for this chunk (vec4), commit next chunk's staged regs, issue chunk c+2
        {
            size_t row = (size_t)(b * L_ + c * SCHUNK + tq);
            *(float4*)(ys + row * E_ + e0 + qc) = *(float4*)&sy[tq][qc];
        }
        if (c + 1 < NCH){
            commit(buf ^ 1);              // waits on in-flight loads; writes other buffer
            if (c + 2 < NCH) issue((c + 2) * SCHUNK);
        }
        __syncthreads();
    }
}

// ---------------- gating: y2 = (ys + W_D*x) * silu(skip) -> bf16 (vec4) ----------------
__global__ __launch_bounds__(256) void gate_k(const float* __restrict__ ys,
                                              const float* __restrict__ xf,
                                              const ushort* __restrict__ skipb,
                                              const float* __restrict__ W_D,
                                              ushort* __restrict__ y2){
    int i4 = blockIdx.x * 256 + threadIdx.x;
    if (i4 >= M_ * E_ / 4) return;
    int idx = i4 * 4;
    int e = idx & (E_ - 1);
    float4 yv = *(const float4*)(ys + idx);
    float4 xv = *(const float4*)(xf + idx);
    ushort4 sv = *(const ushort4*)(skipb + idx);
    float4 wv = *(const float4*)(W_D + e);
    float sk0 = bf2f(sv.x), sk1 = bf2f(sv.y), sk2 = bf2f(sv.z), sk3 = bf2f(sv.w);
    ushort4 o;
    o.x = f2bf((yv.x + wv.x * xv.x) * (sk0 / (1.f + __expf(-sk0))));
    o.y = f2bf((yv.y + wv.y * xv.y) * (sk1 / (1.f + __expf(-sk1))));
    o.z = f2bf((yv.z + wv.z * xv.z) * (sk2 / (1.f + __expf(-sk2))));
    o.w = f2bf((yv.w + wv.w * xv.w) * (sk3 / (1.f + __expf(-sk3))));
    *(ushort4*)(y2 + idx) = o;
}

// ---------------- launch ----------------
extern "C" void kernel_launch(void* const* d_in, const int* in_sizes, int n_in,
                              void* d_out, int out_size, void* d_ws, size_t ws_size,
                              hipStream_t stream){
    const float* resid  = (const float*)d_in[0];
    const float* norm_w = (const float*)d_in[1];
    const float* skip_w = (const float*)d_in[2];
    const float* in_w   = (const float*)d_in[3];
    const float* conv_w = (const float*)d_in[4];
    const float* conv_b = (const float*)d_in[5];
    const float* wd1    = (const float*)d_in[6];
    const float* wd2    = (const float*)d_in[7];
    const float* wd2_b  = (const float*)d_in[8];
    const float* wB     = (const float*)d_in[9];
    const float* wC     = (const float*)d_in[10];
    const float* A_log  = (const float*)d_in[11];
    const float* W_D    = (const float*)d_in[12];
    const float* out_w  = (const float*)d_in[13];
    float* out = (float*)d_out;

    char* ws = (char*)d_ws;
    size_t off = 0;
    auto alloc = [&](size_t bytes) -> char* {
        char* p = ws + off;
        off += (bytes + 255) & ~(size_t)255;
        return p;
    };
    // --- aliased region: wi, wsk, xn, xpre are all dead before delta GEMM runs;
    //     delta (32MB f32) reuses their combined 32MB.
    char* alias_base = ws;
    ushort* wi_b    = (ushort*)alloc((size_t)E_ * D_ * 2);   // 4MB
    ushort* wsk_b   = (ushort*)alloc((size_t)E_ * D_ * 2);   // 4MB
    ushort* xn_b    = (ushort*)alloc((size_t)M_ * D_ * 2);   // 8MB
    ushort* xpre_b  = (ushort*)alloc((size_t)M_ * E_ * 2);   // 16MB
    float*  deltaf  = (float*)alias_base;                    // 32MB alias
    // --- persistent buffers
    ushort* wo_b    = (ushort*)alloc((size_t)D_ * E_ * 2);       // 4MB
    ushort* wd2_bf  = (ushort*)alloc((size_t)E_ * DR_ * 2);      // 256KB
    ushort* W96_b   = (ushort*)alloc((size_t)128 * E_ * 2);      // 512KB
    ushort* skip_b  = (ushort*)alloc((size_t)M_ * E_ * 2);       // 16MB
    float*  xff     = (float*)alloc((size_t)M_ * E_ * 4);        // 32MB
    ushort* xb_b    = (ushort*)alloc((size_t)M_ * E_ * 2);       // 16MB
    ushort* C96_b   = (ushort*)alloc((size_t)M_ * 128 * 2);      // 1MB
    float*  ysf     = (float*)alloc((size_t)M_ * E_ * 4);        // 32MB
    ushort* y2_b    = (ushort*)alloc((size_t)M_ * E_ * 2);       // 16MB
    (void)ws_size; (void)in_sizes; (void)n_in; (void)out_size;

    const int thr = 256;
    auto blocks4 = [](int n){ return (n/4 + 255) / 256; };

    // weight conversions
    cvt4_k<<<blocks4(E_*D_), thr, 0, stream>>>(in_w,   wi_b,   E_*D_/4);
    cvt4_k<<<blocks4(E_*D_), thr, 0, stream>>>(skip_w, wsk_b,  E_*D_/4);
    cvt4_k<<<blocks4(D_*E_), thr, 0, stream>>>(out_w,  wo_b,   D_*E_/4);
    cvt4_k<<<blocks4(E_*DR_), thr, 0, stream>>>(wd2,   wd2_bf, E_*DR_/4);
    cvt4_k<<<blocks4(DR_*E_), thr, 0, stream>>>(wd1,   W96_b,            DR_*E_/4);
    cvt4_k<<<blocks4(N_*E_),  thr, 0, stream>>>(wB,    W96_b + 64*E_,    N_*E_/4);
    cvt4_k<<<blocks4(N_*E_),  thr, 0, stream>>>(wC,    W96_b + 80*E_,    N_*E_/4);
    zero16_k<<<(32*E_ + 255)/256, thr, 0, stream>>>(W96_b + 96*E_, 32*E_);

    // RMSNorm
    rmsnorm_k<<<M_, thr, 0, stream>>>(resid, norm_w, xn_b);

    // in-proj and skip-proj GEMMs: [4096,2048] = [4096,1024] x [2048,1024]^T
    gemm_bt<1><<<dim3(E_/BN, M_/BM), thr, 0, stream>>>(xn_b, wi_b,  xpre_b, nullptr, M_, E_, D_, D_, D_, E_);
    gemm_bt<1><<<dim3(E_/BN, M_/BM), thr, 0, stream>>>(xn_b, wsk_b, skip_b, nullptr, M_, E_, D_, D_, D_, E_);

    // conv + silu
    conv_silu_k<<<(M_*E_/4 + 255)/256, thr, 0, stream>>>(xpre_b, conv_w, conv_b, xff, xb_b);

    // skinny GEMM: C96[4096,128] = x[4096,2048] x W96[128,2048]^T  (cols: 0..63 xr, 64..79 Bm, 80..95 Cm)
    gemm_bt<1><<<dim3(1, M_/BM), thr, 0, stream>>>(xb_b, W96_b, C96_b, nullptr, M_, 128, E_, E_, E_, 128);

    // delta GEMM: delta[4096,2048] = softplus(xr[4096,64] x wd2[2048,64]^T + wd2_b)
    gemm_bt<2><<<dim3(E_/BN, M_/BM), thr, 0, stream>>>(C96_b, wd2_bf, deltaf, wd2_b, M_, E_, DR_, 128, DR_, E_);

    // selective scan
    scan_k<<<dim3(E_/16, B_), thr, 0, stream>>>(deltaf, xff, C96_b, A_log, ysf);

    // gating
    gate_k<<<(M_*E_/4 + 255)/256, thr, 0, stream>>>(ysf, xff, skip_b, W_D, y2_b);

    // out-proj + residual: out[4096,1024] = y2[4096,2048] x out_w[1024,2048]^T + resid
    gemm_bt<3><<<dim3(D_/BN, M_/BM), thr, 0, stream>>>(y2_b, wo_b, out, resid, M_, D_, E_, E_, E_, D_);
}

// Round 3
// 464.178 us; speedup vs baseline: 1.6738x; 1.5497x over previous
//
#include <hip/hip_runtime.h>
#include <hip/hip_bf16.h>

// Problem dims (fixed)
#define B_ 2
#define L_ 2048
#define D_ 1024
#define E_ 2048
#define N_ 16
#define DR_ 64
#define DC_ 4
#define M_ (B_*L_)   // 4096 rows
#define SSEG 16      // scan segments
#define LSEG (L_/SSEG)  // 128

typedef __attribute__((ext_vector_type(8))) short bf16x8;
typedef __attribute__((ext_vector_type(4))) float f32x4;

__device__ __forceinline__ ushort f2bf(float x){
    union { float f; unsigned u; } v; v.f = x;
    unsigned r = v.u + 0x7FFFu + ((v.u >> 16) & 1u);
    return (ushort)(r >> 16);
}
__device__ __forceinline__ float bf2f(ushort u){
    union { unsigned u; float f; } v; v.u = ((unsigned)u) << 16;
    return v.f;
}

// ---------------- convert f32 -> bf16 (vec4) ----------------
__global__ void cvt4_k(const float* __restrict__ in, ushort* __restrict__ out, int n4){
    int i = blockIdx.x * 256 + threadIdx.x;
    if (i < n4){
        float4 v = ((const float4*)in)[i];
        ushort4 o;
        o.x = f2bf(v.x); o.y = f2bf(v.y); o.z = f2bf(v.z); o.w = f2bf(v.w);
        ((ushort4*)out)[i] = o;
    }
}

__global__ void zero16_k(ushort* __restrict__ p, int n){
    int i = blockIdx.x * 256 + threadIdx.x;
    if (i < n) p[i] = 0;
}

// ---------------- RMSNorm -> bf16 ----------------
__global__ __launch_bounds__(256) void rmsnorm_k(const float* __restrict__ resid,
                                                 const float* __restrict__ norm_w,
                                                 ushort* __restrict__ xn){
    int row = blockIdx.x;
    const float4* r = (const float4*)(resid + (size_t)row * D_);
    float4 v = r[threadIdx.x];
    float ss = v.x*v.x + v.y*v.y + v.z*v.z + v.w*v.w;
    for (int m = 32; m; m >>= 1) ss += __shfl_xor(ss, m);
    __shared__ float sred[4];
    if ((threadIdx.x & 63) == 0) sred[threadIdx.x >> 6] = ss;
    __syncthreads();
    float tot = sred[0] + sred[1] + sred[2] + sred[3];
    float scale = rsqrtf(tot / (float)D_ + 1e-5f);
    const float4* wv = (const float4*)norm_w;
    float4 w = wv[threadIdx.x];
    ushort4 o;
    o.x = f2bf(v.x * scale * w.x);
    o.y = f2bf(v.y * scale * w.y);
    o.z = f2bf(v.z * scale * w.z);
    o.w = f2bf(v.w * scale * w.w);
    ((ushort4*)(xn + (size_t)row * D_))[threadIdx.x] = o;
}

// ---------------- GEMM: C[M,N] = A[M,K] * B[N,K]^T, bf16 in, f32 acc ----------------
// EPI: 0 = f32 store, 1 = bf16 store, 2 = softplus(acc + aux[col]) f32 store, 3 = acc + aux[idx] f32 store
#define BM 128
#define BN 128
#define BK 64
#define LDT 72

template<int EPI>
__global__ __launch_bounds__(256)
void gemm_bt(const ushort* __restrict__ A, const ushort* __restrict__ Bm,
             void* __restrict__ Cp, const float* __restrict__ aux,
             int M, int N, int K, int lda, int ldb, int ldc){
    __shared__ __align__(16) ushort As[BM * LDT];
    __shared__ __align__(16) ushort Bs[BN * LDT];
    const int col0 = blockIdx.x * BN;
    const int row0 = blockIdx.y * BM;
    const int tid = threadIdx.x;
    const int lane = tid & 63;
    const int wid = tid >> 6;
    const int wm = wid >> 1, wn = wid & 1;   // 2x2 waves of 64x64
    f32x4 acc[4][4] = {};

    const int lr = tid >> 3;         // 0..31 row within group
    const int lc = (tid & 7) * 8;    // 0..56 col (elements)

    for (int k0 = 0; k0 < K; k0 += BK){
        #pragma unroll
        for (int i = 0; i < 4; ++i){
            int r = lr + 32 * i;
            *(uint4*)(As + r * LDT + lc) =
                *(const uint4*)(A + (size_t)(row0 + r) * lda + k0 + lc);
            *(uint4*)(Bs + r * LDT + lc) =
                *(const uint4*)(Bm + (size_t)(col0 + r) * ldb + k0 + lc);
        }
        __syncthreads();
        #pragma unroll
        for (int kk = 0; kk < 2; ++kk){
            bf16x8 af[4], bfr[4];
            const int krow = lane & 15;
            const int kcol = kk * 32 + (lane >> 4) * 8;
            #pragma unroll
            for (int mi = 0; mi < 4; ++mi)
                af[mi] = *(const bf16x8*)(As + (wm*64 + mi*16 + krow) * LDT + kcol);
            #pragma unroll
            for (int ni = 0; ni < 4; ++ni)
                bfr[ni] = *(const bf16x8*)(Bs + (wn*64 + ni*16 + krow) * LDT + kcol);
            #pragma unroll
            for (int mi = 0; mi < 4; ++mi)
                #pragma unroll
                for (int ni = 0; ni < 4; ++ni)
                    acc[mi][ni] = __builtin_amdgcn_mfma_f32_16x16x32_bf16(af[mi], bfr[ni], acc[mi][ni], 0, 0, 0);
        }
        __syncthreads();
    }

    #pragma unroll
    for (int mi = 0; mi < 4; ++mi)
        #pragma unroll
        for (int ni = 0; ni < 4; ++ni)
            #pragma unroll
            for (int j = 0; j < 4; ++j){
                int r = row0 + wm*64 + mi*16 + (lane >> 4) * 4 + j;
                int c = col0 + wn*64 + ni*16 + (lane & 15);
                size_t idx = (size_t)r * ldc + c;
                float v = acc[mi][ni][j];
                if (EPI == 0){
                    ((float*)Cp)[idx] = v;
                } else if (EPI == 1){
                    ((ushort*)Cp)[idx] = f2bf(v);
                } else if (EPI == 2){
                    float z = v + aux[c];
                    ((float*)Cp)[idx] = (z > 20.f) ? z : log1pf(__expf(z));
                } else {
                    ((float*)Cp)[idx] = v + aux[idx];
                }
            }
}

// ---------------- causal depthwise conv1d + silu (vec4 along e) ----------------
__global__ __launch_bounds__(256) void conv_silu_k(const ushort* __restrict__ xpre,
                                                   const float* __restrict__ conv_w,
                                                   const float* __restrict__ conv_b,
                                                   float* __restrict__ xf,
                                                   ushort* __restrict__ xb){
    int i4 = blockIdx.x * 256 + threadIdx.x;       // index over groups of 4 elems
    if (i4 >= M_ * E_ / 4) return;
    int idx = i4 * 4;
    int e = idx & (E_ - 1);
    int bl = idx >> 11;
    int t = bl & (L_ - 1);
    float acc[4];
    #pragma unroll
    for (int j = 0; j < 4; ++j) acc[j] = conv_b[e + j];
    #pragma unroll
    for (int k = 0; k < 4; ++k){
        int dt = 3 - k;                            // tap k uses x[t - (3-k)], weight conv_w[e][k]
        if (t >= dt){
            ushort4 xv = *(const ushort4*)(xpre + idx - dt * E_);
            acc[0] += bf2f(xv.x) * conv_w[(e+0)*4 + k];
            acc[1] += bf2f(xv.y) * conv_w[(e+1)*4 + k];
            acc[2] += bf2f(xv.z) * conv_w[(e+2)*4 + k];
            acc[3] += bf2f(xv.w) * conv_w[(e+3)*4 + k];
        }
    }
    float4 so; ushort4 sb;
    float* sp = (float*)&so;
    #pragma unroll
    for (int j = 0; j < 4; ++j){
        float s = acc[j] / (1.f + __expf(-acc[j]));
        sp[j] = s;
    }
    sb.x = f2bf(so.x); sb.y = f2bf(so.y); sb.z = f2bf(so.z); sb.w = f2bf(so.w);
    *(float4*)(xf + idx) = so;
    *(ushort4*)(xb + idx) = sb;
}

// ---------------- chunk-parallel selective scan ----------------
// h_t = a_t h_{t-1} + u_t,  a_t = exp(dt*A[e][n]),  u_t = dt*x_t*B_t[n]
// Segment s covers t in [s*LSEG, (s+1)*LSEG). prod(a over seg) = exp(A[e][n] * sum dt).
// Pass 1: local scan from 0 -> F (final), segdt (sum of dt).
// Pass 2 (carry_k): C_0 = 0; C_s = exp(Aen*segdt_{s-1}) * C_{s-1} + F_{s-1}.
// Pass 3: re-scan segment from C_s, compute y, write ys.

// grid (E_/16, SSEG, B_), block 256 = 16 e x 16 n
__global__ __launch_bounds__(256) void seg1_k(const float* __restrict__ delta,
                                              const float* __restrict__ xf,
                                              const ushort* __restrict__ C96,
                                              const float* __restrict__ A_log,
                                              float* __restrict__ F,
                                              float* __restrict__ segdt){
    const int b = blockIdx.z;
    const int s = blockIdx.y;
    const int e0 = blockIdx.x * 16;
    const int n = threadIdx.x & 15;
    const int ei = threadIdx.x >> 4;
    const int e = e0 + ei;
    const float Aen = -__expf(A_log[e * N_ + n]);
    float h = 0.f, sdt = 0.f;
    __shared__ float sd[64][16], sdx[64][16], sB[64][16];
    const int tq = threadIdx.x >> 2;
    const int qc = (threadIdx.x & 3) * 4;

    for (int c = 0; c < LSEG / 64; ++c){
        int t0 = s * LSEG + c * 64;
        {
            size_t row = (size_t)(b * L_ + t0 + tq);
            float4 rd = *(const float4*)(delta + row * E_ + e0 + qc);
            float4 rx = *(const float4*)(xf    + row * E_ + e0 + qc);
            ushort4 rB = *(const ushort4*)(C96 + row * 128 + 64 + qc);
            *(float4*)&sd[tq][qc] = rd;
            float4 dx; dx.x = rd.x*rx.x; dx.y = rd.y*rx.y; dx.z = rd.z*rx.z; dx.w = rd.w*rx.w;
            *(float4*)&sdx[tq][qc] = dx;
            sB[tq][qc+0] = bf2f(rB.x); sB[tq][qc+1] = bf2f(rB.y);
            sB[tq][qc+2] = bf2f(rB.z); sB[tq][qc+3] = bf2f(rB.w);
        }
        __syncthreads();
        #pragma unroll 8
        for (int t = 0; t < 64; ++t){
            float dt = sd[t][ei];
            h = __expf(dt * Aen) * h + sdx[t][ei] * sB[t][n];
            sdt += dt;
        }
        __syncthreads();
    }
    size_t base = ((size_t)(b * SSEG + s) * E_ + e) * N_ + n;
    F[base] = h;
    if (n == 0) segdt[(size_t)(b * SSEG + s) * E_ + e] = sdt;
}

// 65536 threads: sequential carry over SSEG segments per (b,e,n)
__global__ __launch_bounds__(256) void carry_k(const float* __restrict__ F,
                                               const float* __restrict__ segdt,
                                               const float* __restrict__ A_log,
                                               float* __restrict__ carr){
    int idx = blockIdx.x * 256 + threadIdx.x;      // over B_*E_*N_
    int n = idx & 15;
    int e = (idx >> 4) & (E_ - 1);
    int b = idx >> 15;
    const float Aen = -__expf(A_log[e * N_ + n]);
    float c = 0.f;
    #pragma unroll
    for (int s = 0; s < SSEG; ++s){
        size_t base = ((size_t)(b * SSEG + s) * E_ + e) * N_ + n;
        carr[base] = c;
        float P = __expf(Aen * segdt[(size_t)(b * SSEG + s) * E_ + e]);
        c = P * c + F[base];
    }
}

// grid (E_/16, SSEG, B_), block 256
__global__ __launch_bounds__(256) void seg2_k(const float* __restrict__ delta,
                                              const float* __restrict__ xf,
                                              const ushort* __restrict__ C96,
                                              const float* __restrict__ A_log,
                                              const float* __restrict__ carr,
                                              float* __restrict__ ys){
    const int b = blockIdx.z;
    const int s = blockIdx.y;
    const int e0 = blockIdx.x * 16;
    const int n = threadIdx.x & 15;
    const int ei = threadIdx.x >> 4;
    const int e = e0 + ei;
    const float Aen = -__expf(A_log[e * N_ + n]);
    float h = carr[((size_t)(b * SSEG + s) * E_ + e) * N_ + n];
    __shared__ float sd[64][16], sdx[64][16], sB[64][16], sC[64][16], sy[64][16];
    const int tq = threadIdx.x >> 2;
    const int qc = (threadIdx.x & 3) * 4;

    for (int c = 0; c < LSEG / 64; ++c){
        int t0 = s * LSEG + c * 64;
        {
            size_t row = (size_t)(b * L_ + t0 + tq);
            float4 rd = *(const float4*)(delta + row * E_ + e0 + qc);
            float4 rx = *(const float4*)(xf    + row * E_ + e0 + qc);
            ushort4 rB = *(const ushort4*)(C96 + row * 128 + 64 + qc);
            ushort4 rC = *(const ushort4*)(C96 + row * 128 + 80 + qc);
            *(float4*)&sd[tq][qc] = rd;
            float4 dx; dx.x = rd.x*rx.x; dx.y = rd.y*rx.y; dx.z = rd.z*rx.z; dx.w = rd.w*rx.w;
            *(float4*)&sdx[tq][qc] = dx;
            sB[tq][qc+0] = bf2f(rB.x); sB[tq][qc+1] = bf2f(rB.y);
            sB[tq][qc+2] = bf2f(rB.z); sB[tq][qc+3] = bf2f(rB.w);
            sC[tq][qc+0] = bf2f(rC.x); sC[tq][qc+1] = bf2f(rC.y);
            sC[tq][qc+2] = bf2f(rC.z); sC[tq][qc+3] = bf2f(rC.w);
        }
        __syncthreads();
        #pragma unroll 4
        for (int t = 0; t < 64; ++t){
            h = __expf(sd[t][ei] * Aen) * h + sdx[t][ei] * sB[t][n];
            float y = h * sC[t][n];
            y += __shfl_xor(y, 1);
            y += __shfl_xor(y, 2);
            y += __shfl_xor(y, 4);
            y += __shfl_xor(y, 8);
            if (n == 0) sy[t][ei] = y;
        }
        __syncthreads();
        {
            size_t row = (size_t)(b * L_ + t0 + tq);
            *(float4*)(ys + row * E_ + e0 + qc) = *(float4*)&sy[tq][qc];
        }
        __syncthreads();
    }
}

// ---------------- gating: y2 = (ys + W_D*x) * silu(skip) -> bf16 (vec4) ----------------
__global__ __launch_bounds__(256) void gate_k(const float* __restrict__ ys,
                                              const float* __restrict__ xf,
                                              const ushort* __restrict__ skipb,
                                              const float* __restrict__ W_D,
                                              ushort* __restrict__ y2){
    int i4 = blockIdx.x * 256 + threadIdx.x;
    if (i4 >= M_ * E_ / 4) return;
    int idx = i4 * 4;
    int e = idx & (E_ - 1);
    float4 yv = *(const float4*)(ys + idx);
    float4 xv = *(const float4*)(xf + idx);
    ushort4 sv = *(const ushort4*)(skipb + idx);
    float4 wv = *(const float4*)(W_D + e);
    float sk0 = bf2f(sv.x), sk1 = bf2f(sv.y), sk2 = bf2f(sv.z), sk3 = bf2f(sv.w);
    ushort4 o;
    o.x = f2bf((yv.x + wv.x * xv.x) * (sk0 / (1.f + __expf(-sk0))));
    o.y = f2bf((yv.y + wv.y * xv.y) * (sk1 / (1.f + __expf(-sk1))));
    o.z = f2bf((yv.z + wv.z * xv.z) * (sk2 / (1.f + __expf(-sk2))));
    o.w = f2bf((yv.w + wv.w * xv.w) * (sk3 / (1.f + __expf(-sk3))));
    *(ushort4*)(y2 + idx) = o;
}

// ---------------- launch ----------------
extern "C" void kernel_launch(void* const* d_in, const int* in_sizes, int n_in,
                              void* d_out, int out_size, void* d_ws, size_t ws_size,
                              hipStream_t stream){
    const float* resid  = (const float*)d_in[0];
    const float* norm_w = (const float*)d_in[1];
    const float* skip_w = (const float*)d_in[2];
    const float* in_w   = (const float*)d_in[3];
    const float* conv_w = (const float*)d_in[4];
    const float* conv_b = (const float*)d_in[5];
    const float* wd1    = (const float*)d_in[6];
    const float* wd2    = (const float*)d_in[7];
    const float* wd2_b  = (const float*)d_in[8];
    const float* wB     = (const float*)d_in[9];
    const float* wC     = (const float*)d_in[10];
    const float* A_log  = (const float*)d_in[11];
    const float* W_D    = (const float*)d_in[12];
    const float* out_w  = (const float*)d_in[13];
    float* out = (float*)d_out;

    char* ws = (char*)d_ws;
    size_t off = 0;
    auto alloc = [&](size_t bytes) -> char* {
        char* p = ws + off;
        off += (bytes + 255) & ~(size_t)255;
        return p;
    };
    // --- aliased region: wi, wsk, xn, xpre are all dead before delta GEMM runs;
    //     delta (32MB f32) reuses their combined 32MB.
    char* alias_base = ws;
    ushort* wi_b    = (ushort*)alloc((size_t)E_ * D_ * 2);   // 4MB
    ushort* wsk_b   = (ushort*)alloc((size_t)E_ * D_ * 2);   // 4MB
    ushort* xn_b    = (ushort*)alloc((size_t)M_ * D_ * 2);   // 8MB
    ushort* xpre_b  = (ushort*)alloc((size_t)M_ * E_ * 2);   // 16MB
    float*  deltaf  = (float*)alias_base;                    // 32MB alias
    // --- persistent buffers
    ushort* wo_b    = (ushort*)alloc((size_t)D_ * E_ * 2);       // 4MB
    ushort* wd2_bf  = (ushort*)alloc((size_t)E_ * DR_ * 2);      // 256KB
    ushort* W96_b   = (ushort*)alloc((size_t)128 * E_ * 2);      // 512KB
    ushort* skip_b  = (ushort*)alloc((size_t)M_ * E_ * 2);       // 16MB
    float*  xff     = (float*)alloc((size_t)M_ * E_ * 4);        // 32MB
    ushort* xb_b    = (ushort*)alloc((size_t)M_ * E_ * 2);       // 16MB
    ushort* C96_b   = (ushort*)alloc((size_t)M_ * 128 * 2);      // 1MB
    float*  ysf     = (float*)alloc((size_t)M_ * E_ * 4);        // 32MB
    ushort* y2_b    = (ushort*)alloc((size_t)M_ * E_ * 2);       // 16MB
    // --- scan scratch aliases y2_b region (dead until gate_k, which runs after seg2_k)
    //     F: 4MB, carr: 4MB, segdt: 256KB -> 8.25MB <= 16MB
    float* F_buf    = (float*)y2_b;
    float* carr_buf = (float*)((char*)y2_b + (size_t)B_ * SSEG * E_ * N_ * 4);
    float* segdt_buf= (float*)((char*)y2_b + (size_t)2 * B_ * SSEG * E_ * N_ * 4);
    (void)ws_size; (void)in_sizes; (void)n_in; (void)out_size;

    const int thr = 256;
    auto blocks4 = [](int n){ return (n/4 + 255) / 256; };

    // weight conversions
    cvt4_k<<<blocks4(E_*D_), thr, 0, stream>>>(in_w,   wi_b,   E_*D_/4);
    cvt4_k<<<blocks4(E_*D_), thr, 0, stream>>>(skip_w, wsk_b,  E_*D_/4);
    cvt4_k<<<blocks4(D_*E_), thr, 0, stream>>>(out_w,  wo_b,   D_*E_/4);
    cvt4_k<<<blocks4(E_*DR_), thr, 0, stream>>>(wd2,   wd2_bf, E_*DR_/4);
    cvt4_k<<<blocks4(DR_*E_), thr, 0, stream>>>(wd1,   W96_b,            DR_*E_/4);
    cvt4_k<<<blocks4(N_*E_),  thr, 0, stream>>>(wB,    W96_b + 64*E_,    N_*E_/4);
    cvt4_k<<<blocks4(N_*E_),  thr, 0, stream>>>(wC,    W96_b + 80*E_,    N_*E_/4);
    zero16_k<<<(32*E_ + 255)/256, thr, 0, stream>>>(W96_b + 96*E_, 32*E_);

    // RMSNorm
    rmsnorm_k<<<M_, thr, 0, stream>>>(resid, norm_w, xn_b);

    // in-proj and skip-proj GEMMs: [4096,2048] = [4096,1024] x [2048,1024]^T
    gemm_bt<1><<<dim3(E_/BN, M_/BM), thr, 0, stream>>>(xn_b, wi_b,  xpre_b, nullptr, M_, E_, D_, D_, D_, E_);
    gemm_bt<1><<<dim3(E_/BN, M_/BM), thr, 0, stream>>>(xn_b, wsk_b, skip_b, nullptr, M_, E_, D_, D_, D_, E_);

    // conv + silu
    conv_silu_k<<<(M_*E_/4 + 255)/256, thr, 0, stream>>>(xpre_b, conv_w, conv_b, xff, xb_b);

    // skinny GEMM: C96[4096,128] = x[4096,2048] x W96[128,2048]^T  (cols: 0..63 xr, 64..79 Bm, 80..95 Cm)
    gemm_bt<1><<<dim3(1, M_/BM), thr, 0, stream>>>(xb_b, W96_b, C96_b, nullptr, M_, 128, E_, E_, E_, 128);

    // delta GEMM: delta[4096,2048] = softplus(xr[4096,64] x wd2[2048,64]^T + wd2_b)
    gemm_bt<2><<<dim3(E_/BN, M_/BM), thr, 0, stream>>>(C96_b, wd2_bf, deltaf, wd2_b, M_, E_, DR_, 128, DR_, E_);

    // chunk-parallel selective scan
    seg1_k<<<dim3(E_/16, SSEG, B_), thr, 0, stream>>>(deltaf, xff, C96_b, A_log, F_buf, segdt_buf);
    carry_k<<<(B_*E_*N_)/256, thr, 0, stream>>>(F_buf, segdt_buf, A_log, carr_buf);
    seg2_k<<<dim3(E_/16, SSEG, B_), thr, 0, stream>>>(deltaf, xff, C96_b, A_log, carr_buf, ysf);

    // gating
    gate_k<<<(M_*E_/4 + 255)/256, thr, 0, stream>>>(ysf, xff, skip_b, W_D, y2_b);

    // out-proj + residual: out[4096,1024] = y2[4096,2048] x out_w[1024,2048]^T + resid
    gemm_bt<3><<<dim3(D_/BN, M_/BM), thr, 0, stream>>>(y2_b, wo_b, out, resid, M_, D_, E_, E_, E_, D_);
}

// Round 4
// 407.893 us; speedup vs baseline: 1.9048x; 1.1380x over previous
//
#include <hip/hip_runtime.h>
#include <hip/hip_bf16.h>

// Problem dims (fixed)
#define B_ 2
#define L_ 2048
#define D_ 1024
#define E_ 2048
#define N_ 16
#define DR_ 64
#define DC_ 4
#define M_ (B_*L_)   // 4096 rows
#define SSEG 16      // scan segments
#define LSEG (L_/SSEG)  // 128

typedef __attribute__((ext_vector_type(8))) short bf16x8;
typedef __attribute__((ext_vector_type(4))) float f32x4;

__device__ __forceinline__ ushort f2bf(float x){
    union { float f; unsigned u; } v; v.f = x;
    unsigned r = v.u + 0x7FFFu + ((v.u >> 16) & 1u);
    return (ushort)(r >> 16);
}
__device__ __forceinline__ float bf2f(ushort u){
    union { unsigned u; float f; } v; v.u = ((unsigned)u) << 16;
    return v.f;
}

// ---------------- convert f32 -> bf16 (vec4) ----------------
__global__ void cvt4_k(const float* __restrict__ in, ushort* __restrict__ out, int n4){
    int i = blockIdx.x * 256 + threadIdx.x;
    if (i < n4){
        float4 v = ((const float4*)in)[i];
        ushort4 o;
        o.x = f2bf(v.x); o.y = f2bf(v.y); o.z = f2bf(v.z); o.w = f2bf(v.w);
        ((ushort4*)out)[i] = o;
    }
}

__global__ void zero16_k(ushort* __restrict__ p, int n){
    int i = blockIdx.x * 256 + threadIdx.x;
    if (i < n) p[i] = 0;
}

// ---------------- RMSNorm -> bf16 ----------------
__global__ __launch_bounds__(256) void rmsnorm_k(const float* __restrict__ resid,
                                                 const float* __restrict__ norm_w,
                                                 ushort* __restrict__ xn){
    int row = blockIdx.x;
    const float4* r = (const float4*)(resid + (size_t)row * D_);
    float4 v = r[threadIdx.x];
    float ss = v.x*v.x + v.y*v.y + v.z*v.z + v.w*v.w;
    for (int m = 32; m; m >>= 1) ss += __shfl_xor(ss, m);
    __shared__ float sred[4];
    if ((threadIdx.x & 63) == 0) sred[threadIdx.x >> 6] = ss;
    __syncthreads();
    float tot = sred[0] + sred[1] + sred[2] + sred[3];
    float scale = rsqrtf(tot / (float)D_ + 1e-5f);
    const float4* wv = (const float4*)norm_w;
    float4 w = wv[threadIdx.x];
    ushort4 o;
    o.x = f2bf(v.x * scale * w.x);
    o.y = f2bf(v.y * scale * w.y);
    o.z = f2bf(v.z * scale * w.z);
    o.w = f2bf(v.w * scale * w.w);
    ((ushort4*)(xn + (size_t)row * D_))[threadIdx.x] = o;
}

// ---------------- GEMM: C[M,N] = A[M,K] * B[N,K]^T, bf16 in, f32 acc ----------------
// EPI: 0 = f32 store, 1 = bf16 store, 2 = softplus(acc + aux[col]) f32 store, 3 = acc + aux[idx] f32 store
#define BM 128
#define BN 128
#define BK 64
#define LDT 72

template<int EPI>
__global__ __launch_bounds__(256)
void gemm_bt(const ushort* __restrict__ A, const ushort* __restrict__ Bm,
             void* __restrict__ Cp, const float* __restrict__ aux,
             int M, int N, int K, int lda, int ldb, int ldc){
    __shared__ __align__(16) ushort As[BM * LDT];
    __shared__ __align__(16) ushort Bs[BN * LDT];
    const int col0 = blockIdx.x * BN;
    const int row0 = blockIdx.y * BM;
    const int tid = threadIdx.x;
    const int lane = tid & 63;
    const int wid = tid >> 6;
    const int wm = wid >> 1, wn = wid & 1;   // 2x2 waves of 64x64
    f32x4 acc[4][4] = {};

    const int lr = tid >> 3;         // 0..31 row within group
    const int lc = (tid & 7) * 8;    // 0..56 col (elements)

    for (int k0 = 0; k0 < K; k0 += BK){
        #pragma unroll
        for (int i = 0; i < 4; ++i){
            int r = lr + 32 * i;
            *(uint4*)(As + r * LDT + lc) =
                *(const uint4*)(A + (size_t)(row0 + r) * lda + k0 + lc);
            *(uint4*)(Bs + r * LDT + lc) =
                *(const uint4*)(Bm + (size_t)(col0 + r) * ldb + k0 + lc);
        }
        __syncthreads();
        #pragma unroll
        for (int kk = 0; kk < 2; ++kk){
            bf16x8 af[4], bfr[4];
            const int krow = lane & 15;
            const int kcol = kk * 32 + (lane >> 4) * 8;
            #pragma unroll
            for (int mi = 0; mi < 4; ++mi)
                af[mi] = *(const bf16x8*)(As + (wm*64 + mi*16 + krow) * LDT + kcol);
            #pragma unroll
            for (int ni = 0; ni < 4; ++ni)
                bfr[ni] = *(const bf16x8*)(Bs + (wn*64 + ni*16 + krow) * LDT + kcol);
            #pragma unroll
            for (int mi = 0; mi < 4; ++mi)
                #pragma unroll
                for (int ni = 0; ni < 4; ++ni)
                    acc[mi][ni] = __builtin_amdgcn_mfma_f32_16x16x32_bf16(af[mi], bfr[ni], acc[mi][ni], 0, 0, 0);
        }
        __syncthreads();
    }

    #pragma unroll
    for (int mi = 0; mi < 4; ++mi)
        #pragma unroll
        for (int ni = 0; ni < 4; ++ni)
            #pragma unroll
            for (int j = 0; j < 4; ++j){
                int r = row0 + wm*64 + mi*16 + (lane >> 4) * 4 + j;
                int c = col0 + wn*64 + ni*16 + (lane & 15);
                size_t idx = (size_t)r * ldc + c;
                float v = acc[mi][ni][j];
                if (EPI == 0){
                    ((float*)Cp)[idx] = v;
                } else if (EPI == 1){
                    ((ushort*)Cp)[idx] = f2bf(v);
                } else if (EPI == 2){
                    float z = v + aux[c];
                    ((float*)Cp)[idx] = (z > 20.f) ? z : log1pf(__expf(z));
                } else {
                    ((float*)Cp)[idx] = v + aux[idx];
                }
            }
}

// ---------------- causal depthwise conv1d + silu (vec4 along e) ----------------
__global__ __launch_bounds__(256) void conv_silu_k(const ushort* __restrict__ xpre,
                                                   const float* __restrict__ conv_w,
                                                   const float* __restrict__ conv_b,
                                                   float* __restrict__ xf,
                                                   ushort* __restrict__ xb){
    int i4 = blockIdx.x * 256 + threadIdx.x;       // index over groups of 4 elems
    if (i4 >= M_ * E_ / 4) return;
    int idx = i4 * 4;
    int e = idx & (E_ - 1);
    int bl = idx >> 11;
    int t = bl & (L_ - 1);
    float acc[4];
    #pragma unroll
    for (int j = 0; j < 4; ++j) acc[j] = conv_b[e + j];
    #pragma unroll
    for (int k = 0; k < 4; ++k){
        int dt = 3 - k;                            // tap k uses x[t - (3-k)], weight conv_w[e][k]
        if (t >= dt){
            ushort4 xv = *(const ushort4*)(xpre + idx - dt * E_);
            acc[0] += bf2f(xv.x) * conv_w[(e+0)*4 + k];
            acc[1] += bf2f(xv.y) * conv_w[(e+1)*4 + k];
            acc[2] += bf2f(xv.z) * conv_w[(e+2)*4 + k];
            acc[3] += bf2f(xv.w) * conv_w[(e+3)*4 + k];
        }
    }
    float4 so; ushort4 sb;
    float* sp = (float*)&so;
    #pragma unroll
    for (int j = 0; j < 4; ++j){
        float s = acc[j] / (1.f + __expf(-acc[j]));
        sp[j] = s;
    }
    sb.x = f2bf(so.x); sb.y = f2bf(so.y); sb.z = f2bf(so.z); sb.w = f2bf(so.w);
    *(float4*)(xf + idx) = so;
    *(ushort4*)(xb + idx) = sb;
}

// ---------------- chunk-parallel selective scan ----------------
// h_t = a_t h_{t-1} + u_t,  a_t = exp(dt*A[e][n]),  u_t = dt*x_t*B_t[n]
// Pass 1 (seg1): local scan from 0 -> F (final state), segdt (sum of dt).
// Pass 2 (carry_k): C_0 = 0; C_s = exp(Aen*segdt_{s-1}) * C_{s-1} + F_{s-1}.
// Pass 3 (seg2): re-scan segment from C_s, compute y, write ys.
// LDS tiles transposed [16][68] so inner loop reads 4 t's per ds_read_b128.

#define SLD 68   // stride 68 floats = 272B: 16B-aligned, 2-way max bank aliasing

// grid (E_/16, SSEG, B_), block 256 = 16 e x 16 n
__global__ __launch_bounds__(256) void seg1_k(const float* __restrict__ delta,
                                              const float* __restrict__ xf,
                                              const ushort* __restrict__ C96,
                                              const float* __restrict__ A_log,
                                              float* __restrict__ F,
                                              float* __restrict__ segdt){
    const int b = blockIdx.z;
    const int s = blockIdx.y;
    const int e0 = blockIdx.x * 16;
    const int n = threadIdx.x & 15;
    const int ei = threadIdx.x >> 4;
    const int e = e0 + ei;
    const float Aen = -__expf(A_log[e * N_ + n]);
    float h = 0.f, sdt = 0.f;
    __shared__ float sd[16][SLD], sdx[16][SLD], sB[16][SLD];
    const int tq = threadIdx.x >> 2;        // 0..63 : t row staged
    const int qc = (threadIdx.x & 3) * 4;   // 4-col group in e/n dim

    for (int c = 0; c < LSEG / 64; ++c){
        int t0 = s * LSEG + c * 64;
        {
            size_t row = (size_t)(b * L_ + t0 + tq);
            float4 rd = *(const float4*)(delta + row * E_ + e0 + qc);
            float4 rx = *(const float4*)(xf    + row * E_ + e0 + qc);
            ushort4 rB = *(const ushort4*)(C96 + row * 128 + 64 + qc);
            sd[qc+0][tq] = rd.x; sd[qc+1][tq] = rd.y; sd[qc+2][tq] = rd.z; sd[qc+3][tq] = rd.w;
            sdx[qc+0][tq] = rd.x*rx.x; sdx[qc+1][tq] = rd.y*rx.y;
            sdx[qc+2][tq] = rd.z*rx.z; sdx[qc+3][tq] = rd.w*rx.w;
            sB[qc+0][tq] = bf2f(rB.x); sB[qc+1][tq] = bf2f(rB.y);
            sB[qc+2][tq] = bf2f(rB.z); sB[qc+3][tq] = bf2f(rB.w);
        }
        __syncthreads();
        #pragma unroll
        for (int t = 0; t < 64; t += 4){
            float4 d4  = *(const float4*)&sd[ei][t];
            float4 dx4 = *(const float4*)&sdx[ei][t];
            float4 b4  = *(const float4*)&sB[n][t];
            h = __expf(d4.x * Aen) * h + dx4.x * b4.x;
            h = __expf(d4.y * Aen) * h + dx4.y * b4.y;
            h = __expf(d4.z * Aen) * h + dx4.z * b4.z;
            h = __expf(d4.w * Aen) * h + dx4.w * b4.w;
            sdt += d4.x + d4.y + d4.z + d4.w;
        }
        __syncthreads();
    }
    size_t base = ((size_t)(b * SSEG + s) * E_ + e) * N_ + n;
    F[base] = h;
    if (n == 0) segdt[(size_t)(b * SSEG + s) * E_ + e] = sdt;
}

// 65536 threads: sequential carry over SSEG segments per (b,e,n)
__global__ __launch_bounds__(256) void carry_k(const float* __restrict__ F,
                                               const float* __restrict__ segdt,
                                               const float* __restrict__ A_log,
                                               float* __restrict__ carr){
    int idx = blockIdx.x * 256 + threadIdx.x;      // over B_*E_*N_
    int n = idx & 15;
    int e = (idx >> 4) & (E_ - 1);
    int b = idx >> 15;
    const float Aen = -__expf(A_log[e * N_ + n]);
    float c = 0.f;
    #pragma unroll
    for (int s = 0; s < SSEG; ++s){
        size_t base = ((size_t)(b * SSEG + s) * E_ + e) * N_ + n;
        carr[base] = c;
        float P = __expf(Aen * segdt[(size_t)(b * SSEG + s) * E_ + e]);
        c = P * c + F[base];
    }
}

// grid (E_/16, SSEG, B_), block 256
__global__ __launch_bounds__(256) void seg2_k(const float* __restrict__ delta,
                                              const float* __restrict__ xf,
                                              const ushort* __restrict__ C96,
                                              const float* __restrict__ A_log,
                                              const float* __restrict__ carr,
                                              float* __restrict__ ys){
    const int b = blockIdx.z;
    const int s = blockIdx.y;
    const int e0 = blockIdx.x * 16;
    const int n = threadIdx.x & 15;
    const int ei = threadIdx.x >> 4;
    const int e = e0 + ei;
    const float Aen = -__expf(A_log[e * N_ + n]);
    float h = carr[((size_t)(b * SSEG + s) * E_ + e) * N_ + n];
    __shared__ float sd[16][SLD], sdx[16][SLD], sB[16][SLD], sC[16][SLD];
    __shared__ float sy[64][16];
    const int tq = threadIdx.x >> 2;
    const int qc = (threadIdx.x & 3) * 4;

    for (int c = 0; c < LSEG / 64; ++c){
        int t0 = s * LSEG + c * 64;
        {
            size_t row = (size_t)(b * L_ + t0 + tq);
            float4 rd = *(const float4*)(delta + row * E_ + e0 + qc);
            float4 rx = *(const float4*)(xf    + row * E_ + e0 + qc);
            ushort4 rB = *(const ushort4*)(C96 + row * 128 + 64 + qc);
            ushort4 rC = *(const ushort4*)(C96 + row * 128 + 80 + qc);
            sd[qc+0][tq] = rd.x; sd[qc+1][tq] = rd.y; sd[qc+2][tq] = rd.z; sd[qc+3][tq] = rd.w;
            sdx[qc+0][tq] = rd.x*rx.x; sdx[qc+1][tq] = rd.y*rx.y;
            sdx[qc+2][tq] = rd.z*rx.z; sdx[qc+3][tq] = rd.w*rx.w;
            sB[qc+0][tq] = bf2f(rB.x); sB[qc+1][tq] = bf2f(rB.y);
            sB[qc+2][tq] = bf2f(rB.z); sB[qc+3][tq] = bf2f(rB.w);
            sC[qc+0][tq] = bf2f(rC.x); sC[qc+1][tq] = bf2f(rC.y);
            sC[qc+2][tq] = bf2f(rC.z); sC[qc+3][tq] = bf2f(rC.w);
        }
        __syncthreads();
        #pragma unroll
        for (int t = 0; t < 64; t += 4){
            float4 d4  = *(const float4*)&sd[ei][t];
            float4 dx4 = *(const float4*)&sdx[ei][t];
            float4 b4  = *(const float4*)&sB[n][t];
            float4 c4  = *(const float4*)&sC[n][t];
            float y0, y1, y2, y3;
            h = __expf(d4.x * Aen) * h + dx4.x * b4.x;  y0 = h * c4.x;
            h = __expf(d4.y * Aen) * h + dx4.y * b4.y;  y1 = h * c4.y;
            h = __expf(d4.z * Aen) * h + dx4.z * b4.z;  y2 = h * c4.z;
            h = __expf(d4.w * Aen) * h + dx4.w * b4.w;  y3 = h * c4.w;
            // 4-value 16-lane butterfly reduce: 5 shfls total
            float s01 = (n & 1) ? y0 : y1;
            float r01 = __shfl_xor(s01, 1);
            float s23 = (n & 1) ? y2 : y3;
            float r23 = __shfl_xor(s23, 1);
            float va, vb;
            if (n & 1){ va = y1 + r01; vb = y3 + r23; }
            else      { va = y0 + r01; vb = y2 + r23; }
            float s2 = (n & 2) ? va : vb;
            float r2 = __shfl_xor(s2, 2);
            float v = ((n & 2) ? vb : va) + r2;
            v += __shfl_xor(v, 4);
            v += __shfl_xor(v, 8);
            if (n < 4) sy[t + n][ei] = v;   // lane n holds sum for t-offset n&3
        }
        __syncthreads();
        {
            size_t row = (size_t)(b * L_ + t0 + tq);
            *(float4*)(ys + row * E_ + e0 + qc) = *(float4*)&sy[tq][qc];
        }
        __syncthreads();
    }
}

// ---------------- gating: y2 = (ys + W_D*x) * silu(skip) -> bf16 (vec4) ----------------
__global__ __launch_bounds__(256) void gate_k(const float* __restrict__ ys,
                                              const float* __restrict__ xf,
                                              const ushort* __restrict__ skipb,
                                              const float* __restrict__ W_D,
                                              ushort* __restrict__ y2){
    int i4 = blockIdx.x * 256 + threadIdx.x;
    if (i4 >= M_ * E_ / 4) return;
    int idx = i4 * 4;
    int e = idx & (E_ - 1);
    float4 yv = *(const float4*)(ys + idx);
    float4 xv = *(const float4*)(xf + idx);
    ushort4 sv = *(const ushort4*)(skipb + idx);
    float4 wv = *(const float4*)(W_D + e);
    float sk0 = bf2f(sv.x), sk1 = bf2f(sv.y), sk2 = bf2f(sv.z), sk3 = bf2f(sv.w);
    ushort4 o;
    o.x = f2bf((yv.x + wv.x * xv.x) * (sk0 / (1.f + __expf(-sk0))));
    o.y = f2bf((yv.y + wv.y * xv.y) * (sk1 / (1.f + __expf(-sk1))));
    o.z = f2bf((yv.z + wv.z * xv.z) * (sk2 / (1.f + __expf(-sk2))));
    o.w = f2bf((yv.w + wv.w * xv.w) * (sk3 / (1.f + __expf(-sk3))));
    *(ushort4*)(y2 + idx) = o;
}

// ---------------- launch ----------------
extern "C" void kernel_launch(void* const* d_in, const int* in_sizes, int n_in,
                              void* d_out, int out_size, void* d_ws, size_t ws_size,
                              hipStream_t stream){
    const float* resid  = (const float*)d_in[0];
    const float* norm_w = (const float*)d_in[1];
    const float* skip_w = (const float*)d_in[2];
    const float* in_w   = (const float*)d_in[3];
    const float* conv_w = (const float*)d_in[4];
    const float* conv_b = (const float*)d_in[5];
    const float* wd1    = (const float*)d_in[6];
    const float* wd2    = (const float*)d_in[7];
    const float* wd2_b  = (const float*)d_in[8];
    const float* wB     = (const float*)d_in[9];
    const float* wC     = (const float*)d_in[10];
    const float* A_log  = (const float*)d_in[11];
    const float* W_D    = (const float*)d_in[12];
    const float* out_w  = (const float*)d_in[13];
    float* out = (float*)d_out;

    char* ws = (char*)d_ws;
    size_t off = 0;
    auto alloc = [&](size_t bytes) -> char* {
        char* p = ws + off;
        off += (bytes + 255) & ~(size_t)255;
        return p;
    };
    // --- aliased region: wi, wsk, xn, xpre are all dead before delta GEMM runs;
    //     delta (32MB f32) reuses their combined 32MB.
    char* alias_base = ws;
    ushort* wi_b    = (ushort*)alloc((size_t)E_ * D_ * 2);   // 4MB
    ushort* wsk_b   = (ushort*)alloc((size_t)E_ * D_ * 2);   // 4MB
    ushort* xn_b    = (ushort*)alloc((size_t)M_ * D_ * 2);   // 8MB
    ushort* xpre_b  = (ushort*)alloc((size_t)M_ * E_ * 2);   // 16MB
    float*  deltaf  = (float*)alias_base;                    // 32MB alias
    // --- persistent buffers
    ushort* wo_b    = (ushort*)alloc((size_t)D_ * E_ * 2);       // 4MB
    ushort* wd2_bf  = (ushort*)alloc((size_t)E_ * DR_ * 2);      // 256KB
    ushort* W96_b   = (ushort*)alloc((size_t)128 * E_ * 2);      // 512KB
    ushort* skip_b  = (ushort*)alloc((size_t)M_ * E_ * 2);       // 16MB
    float*  xff     = (float*)alloc((size_t)M_ * E_ * 4);        // 32MB
    ushort* xb_b    = (ushort*)alloc((size_t)M_ * E_ * 2);       // 16MB
    ushort* C96_b   = (ushort*)alloc((size_t)M_ * 128 * 2);      // 1MB
    float*  ysf     = (float*)alloc((size_t)M_ * E_ * 4);        // 32MB
    ushort* y2_b    = (ushort*)alloc((size_t)M_ * E_ * 2);       // 16MB
    // --- scan scratch aliases y2_b region (dead until gate_k, which runs after seg2_k)
    float* F_buf    = (float*)y2_b;
    float* carr_buf = (float*)((char*)y2_b + (size_t)B_ * SSEG * E_ * N_ * 4);
    float* segdt_buf= (float*)((char*)y2_b + (size_t)2 * B_ * SSEG * E_ * N_ * 4);
    (void)ws_size; (void)in_sizes; (void)n_in; (void)out_size;

    const int thr = 256;
    auto blocks4 = [](int n){ return (n/4 + 255) / 256; };

    // weight conversions
    cvt4_k<<<blocks4(E_*D_), thr, 0, stream>>>(in_w,   wi_b,   E_*D_/4);
    cvt4_k<<<blocks4(E_*D_), thr, 0, stream>>>(skip_w, wsk_b,  E_*D_/4);
    cvt4_k<<<blocks4(D_*E_), thr, 0, stream>>>(out_w,  wo_b,   D_*E_/4);
    cvt4_k<<<blocks4(E_*DR_), thr, 0, stream>>>(wd2,   wd2_bf, E_*DR_/4);
    cvt4_k<<<blocks4(DR_*E_), thr, 0, stream>>>(wd1,   W96_b,            DR_*E_/4);
    cvt4_k<<<blocks4(N_*E_),  thr, 0, stream>>>(wB,    W96_b + 64*E_,    N_*E_/4);
    cvt4_k<<<blocks4(N_*E_),  thr, 0, stream>>>(wC,    W96_b + 80*E_,    N_*E_/4);
    zero16_k<<<(32*E_ + 255)/256, thr, 0, stream>>>(W96_b + 96*E_, 32*E_);

    // RMSNorm
    rmsnorm_k<<<M_, thr, 0, stream>>>(resid, norm_w, xn_b);

    // in-proj and skip-proj GEMMs: [4096,2048] = [4096,1024] x [2048,1024]^T
    gemm_bt<1><<<dim3(E_/BN, M_/BM), thr, 0, stream>>>(xn_b, wi_b,  xpre_b, nullptr, M_, E_, D_, D_, D_, E_);
    gemm_bt<1><<<dim3(E_/BN, M_/BM), thr, 0, stream>>>(xn_b, wsk_b, skip_b, nullptr, M_, E_, D_, D_, D_, E_);

    // conv + silu
    conv_silu_k<<<(M_*E_/4 + 255)/256, thr, 0, stream>>>(xpre_b, conv_w, conv_b, xff, xb_b);

    // skinny GEMM: C96[4096,128] = x[4096,2048] x W96[128,2048]^T  (cols: 0..63 xr, 64..79 Bm, 80..95 Cm)
    gemm_bt<1><<<dim3(1, M_/BM), thr, 0, stream>>>(xb_b, W96_b, C96_b, nullptr, M_, 128, E_, E_, E_, 128);

    // delta GEMM: delta[4096,2048] = softplus(xr[4096,64] x wd2[2048,64]^T + wd2_b)
    gemm_bt<2><<<dim3(E_/BN, M_/BM), thr, 0, stream>>>(C96_b, wd2_bf, deltaf, wd2_b, M_, E_, DR_, 128, DR_, E_);

    // chunk-parallel selective scan
    seg1_k<<<dim3(E_/16, SSEG, B_), thr, 0, stream>>>(deltaf, xff, C96_b, A_log, F_buf, segdt_buf);
    carry_k<<<(B_*E_*N_)/256, thr, 0, stream>>>(F_buf, segdt_buf, A_log, carr_buf);
    seg2_k<<<dim3(E_/16, SSEG, B_), thr, 0, stream>>>(deltaf, xff, C96_b, A_log, carr_buf, ysf);

    // gating
    gate_k<<<(M_*E_/4 + 255)/256, thr, 0, stream>>>(ysf, xff, skip_b, W_D, y2_b);

    // out-proj + residual: out[4096,1024] = y2[4096,2048] x out_w[1024,2048]^T + resid
    gemm_bt<3><<<dim3(D_/BN, M_/BM), thr, 0, stream>>>(y2_b, wo_b, out, resid, M_, D_, E_, E_, E_, D_);
}

// Round 5
// 350.573 us; speedup vs baseline: 2.2162x; 1.1635x over previous
//
#include <hip/hip_runtime.h>
#include <hip/hip_bf16.h>

// Problem dims (fixed)
#define B_ 2
#define L_ 2048
#define D_ 1024
#define E_ 2048
#define N_ 16
#define DR_ 64
#define DC_ 4
#define M_ (B_*L_)   // 4096 rows
#define SSEG 16      // scan segments
#define LSEG (L_/SSEG)  // 128
#define KS_ 8        // split-K factor for C96 GEMM

typedef __attribute__((ext_vector_type(8))) short bf16x8;
typedef __attribute__((ext_vector_type(4))) float f32x4;

__device__ __forceinline__ ushort f2bf(float x){
    union { float f; unsigned u; } v; v.f = x;
    unsigned r = v.u + 0x7FFFu + ((v.u >> 16) & 1u);
    return (ushort)(r >> 16);
}
__device__ __forceinline__ float bf2f(ushort u){
    union { unsigned u; float f; } v; v.u = ((unsigned)u) << 16;
    return v.f;
}

// async global->LDS, 16B per lane. LDS dest = uniform base + lane*16;
// lane l covers elements [base_e + l*8, +8). Source gptr is per-lane.
__device__ __forceinline__ void gld16(const ushort* g, ushort* l){
    __builtin_amdgcn_global_load_lds(
        (const __attribute__((address_space(1))) unsigned int*)g,
        (__attribute__((address_space(3))) unsigned int*)l,
        16, 0, 0);
}

// ---------------- convert f32 -> bf16 (vec4) ----------------
__global__ void cvt4_k(const float* __restrict__ in, ushort* __restrict__ out, int n4){
    int i = blockIdx.x * 256 + threadIdx.x;
    if (i < n4){
        float4 v = ((const float4*)in)[i];
        ushort4 o;
        o.x = f2bf(v.x); o.y = f2bf(v.y); o.z = f2bf(v.z); o.w = f2bf(v.w);
        ((ushort4*)out)[i] = o;
    }
}

__global__ void zero16_k(ushort* __restrict__ p, int n){
    int i = blockIdx.x * 256 + threadIdx.x;
    if (i < n) p[i] = 0;
}

// ---------------- RMSNorm -> bf16 ----------------
__global__ __launch_bounds__(256) void rmsnorm_k(const float* __restrict__ resid,
                                                 const float* __restrict__ norm_w,
                                                 ushort* __restrict__ xn){
    int row = blockIdx.x;
    const float4* r = (const float4*)(resid + (size_t)row * D_);
    float4 v = r[threadIdx.x];
    float ss = v.x*v.x + v.y*v.y + v.z*v.z + v.w*v.w;
    for (int m = 32; m; m >>= 1) ss += __shfl_xor(ss, m);
    __shared__ float sred[4];
    if ((threadIdx.x & 63) == 0) sred[threadIdx.x >> 6] = ss;
    __syncthreads();
    float tot = sred[0] + sred[1] + sred[2] + sred[3];
    float scale = rsqrtf(tot / (float)D_ + 1e-5f);
    const float4* wv = (const float4*)norm_w;
    float4 w = wv[threadIdx.x];
    ushort4 o;
    o.x = f2bf(v.x * scale * w.x);
    o.y = f2bf(v.y * scale * w.y);
    o.z = f2bf(v.z * scale * w.z);
    o.w = f2bf(v.w * scale * w.w);
    ((ushort4*)(xn + (size_t)row * D_))[threadIdx.x] = o;
}

// ---------------- GEMM: C[M,N] = A[M,K] * B[N,K]^T, bf16 in, f32 acc ----------------
// global_load_lds width-16 staging into LINEAR LDS [128][64] (m97 structure).
// EPI: 1 = bf16 store, 3 = acc + aux[idx] f32 store
#define BM 128
#define BN 128
#define BK 64

template<int EPI>
__global__ __launch_bounds__(256)
void gemm_bt(const ushort* __restrict__ A, const ushort* __restrict__ Bm,
             void* __restrict__ Cp, const float* __restrict__ aux,
             int M, int N, int K, int lda, int ldb, int ldc){
    __shared__ __align__(16) ushort As[BM * BK];
    __shared__ __align__(16) ushort Bs[BN * BK];
    const int col0 = blockIdx.x * BN;
    const int row0 = blockIdx.y * BM;
    const int tid = threadIdx.x;
    const int lane = tid & 63;
    const int wid = tid >> 6;
    const int wm = wid >> 1, wn = wid & 1;   // 2x2 waves of 64x64
    f32x4 acc[4][4] = {};

    const int l8 = lane >> 3;        // row within 8-row group
    const int c8 = (lane & 7) * 8;   // col (elements)

    for (int k0 = 0; k0 < K; k0 += BK){
        #pragma unroll
        for (int i = 0; i < 4; ++i){
            const int R0 = wid * 32 + i * 8;   // 8 rows per instr
            gld16(A + (size_t)(row0 + R0 + l8) * lda + k0 + c8, As + R0 * BK);
            gld16(Bm + (size_t)(col0 + R0 + l8) * ldb + k0 + c8, Bs + R0 * BK);
        }
        __syncthreads();   // drains vmcnt before barrier
        #pragma unroll
        for (int kk = 0; kk < 2; ++kk){
            bf16x8 af[4], bfr[4];
            const int krow = lane & 15;
            const int kcol = kk * 32 + (lane >> 4) * 8;
            #pragma unroll
            for (int mi = 0; mi < 4; ++mi)
                af[mi] = *(const bf16x8*)(As + (wm*64 + mi*16 + krow) * BK + kcol);
            #pragma unroll
            for (int ni = 0; ni < 4; ++ni)
                bfr[ni] = *(const bf16x8*)(Bs + (wn*64 + ni*16 + krow) * BK + kcol);
            #pragma unroll
            for (int mi = 0; mi < 4; ++mi)
                #pragma unroll
                for (int ni = 0; ni < 4; ++ni)
                    acc[mi][ni] = __builtin_amdgcn_mfma_f32_16x16x32_bf16(af[mi], bfr[ni], acc[mi][ni], 0, 0, 0);
        }
        __syncthreads();
    }

    #pragma unroll
    for (int mi = 0; mi < 4; ++mi)
        #pragma unroll
        for (int ni = 0; ni < 4; ++ni)
            #pragma unroll
            for (int j = 0; j < 4; ++j){
                int r = row0 + wm*64 + mi*16 + (lane >> 4) * 4 + j;
                int c = col0 + wn*64 + ni*16 + (lane & 15);
                size_t idx = (size_t)r * ldc + c;
                float v = acc[mi][ni][j];
                if (EPI == 1){
                    ((ushort*)Cp)[idx] = f2bf(v);
                } else {
                    ((float*)Cp)[idx] = v + aux[idx];
                }
            }
}

// ---------------- C96 GEMM, split-K: part[ks][4096][128] f32 partials ----------------
// A = xb [4096][2048], Bm = W96 [128][2048]; each block does K-chunk of 256.
__global__ __launch_bounds__(256)
void gemm_c96_sk(const ushort* __restrict__ A, const ushort* __restrict__ Bm,
                 float* __restrict__ part){
    __shared__ __align__(16) ushort As[BM * BK];
    __shared__ __align__(16) ushort Bs[BN * BK];
    const int ks = blockIdx.x;
    const int row0 = blockIdx.y * BM;
    const int tid = threadIdx.x;
    const int lane = tid & 63;
    const int wid = tid >> 6;
    const int wm = wid >> 1, wn = wid & 1;
    f32x4 acc[4][4] = {};
    const int l8 = lane >> 3;
    const int c8 = (lane & 7) * 8;

    for (int k0 = ks * (E_ / KS_); k0 < (ks + 1) * (E_ / KS_); k0 += BK){
        #pragma unroll
        for (int i = 0; i < 4; ++i){
            const int R0 = wid * 32 + i * 8;
            gld16(A + (size_t)(row0 + R0 + l8) * E_ + k0 + c8, As + R0 * BK);
            gld16(Bm + (size_t)(R0 + l8) * E_ + k0 + c8, Bs + R0 * BK);
        }
        __syncthreads();
        #pragma unroll
        for (int kk = 0; kk < 2; ++kk){
            bf16x8 af[4], bfr[4];
            const int krow = lane & 15;
            const int kcol = kk * 32 + (lane >> 4) * 8;
            #pragma unroll
            for (int mi = 0; mi < 4; ++mi)
                af[mi] = *(const bf16x8*)(As + (wm*64 + mi*16 + krow) * BK + kcol);
            #pragma unroll
            for (int ni = 0; ni < 4; ++ni)
                bfr[ni] = *(const bf16x8*)(Bs + (wn*64 + ni*16 + krow) * BK + kcol);
            #pragma unroll
            for (int mi = 0; mi < 4; ++mi)
                #pragma unroll
                for (int ni = 0; ni < 4; ++ni)
                    acc[mi][ni] = __builtin_amdgcn_mfma_f32_16x16x32_bf16(af[mi], bfr[ni], acc[mi][ni], 0, 0, 0);
        }
        __syncthreads();
    }
    float* dst = part + (size_t)ks * M_ * 128;
    #pragma unroll
    for (int mi = 0; mi < 4; ++mi)
        #pragma unroll
        for (int ni = 0; ni < 4; ++ni)
            #pragma unroll
            for (int j = 0; j < 4; ++j){
                int r = row0 + wm*64 + mi*16 + (lane >> 4) * 4 + j;
                int c = wn*64 + ni*16 + (lane & 15);
                dst[(size_t)r * 128 + c] = acc[mi][ni][j];
            }
}

__global__ __launch_bounds__(256) void c96_reduce_k(const float* __restrict__ part,
                                                    ushort* __restrict__ C96){
    int i4 = blockIdx.x * 256 + threadIdx.x;     // over M_*128/4
    float4 a = *(const float4*)(part + (size_t)i4 * 4);
    #pragma unroll
    for (int k = 1; k < KS_; ++k){
        float4 b = *(const float4*)(part + (size_t)k * M_ * 128 + (size_t)i4 * 4);
        a.x += b.x; a.y += b.y; a.z += b.z; a.w += b.w;
    }
    ushort4 o;
    o.x = f2bf(a.x); o.y = f2bf(a.y); o.z = f2bf(a.z); o.w = f2bf(a.w);
    *(ushort4*)(C96 + (size_t)i4 * 4) = o;
}

// ---------------- causal depthwise conv1d + silu (vec4 along e) ----------------
__global__ __launch_bounds__(256) void conv_silu_k(const ushort* __restrict__ xpre,
                                                   const float* __restrict__ conv_w,
                                                   const float* __restrict__ conv_b,
                                                   float* __restrict__ xf,
                                                   ushort* __restrict__ xb){
    int i4 = blockIdx.x * 256 + threadIdx.x;
    if (i4 >= M_ * E_ / 4) return;
    int idx = i4 * 4;
    int e = idx & (E_ - 1);
    int bl = idx >> 11;
    int t = bl & (L_ - 1);
    float acc[4];
    #pragma unroll
    for (int j = 0; j < 4; ++j) acc[j] = conv_b[e + j];
    #pragma unroll
    for (int k = 0; k < 4; ++k){
        int dt = 3 - k;
        if (t >= dt){
            ushort4 xv = *(const ushort4*)(xpre + idx - dt * E_);
            acc[0] += bf2f(xv.x) * conv_w[(e+0)*4 + k];
            acc[1] += bf2f(xv.y) * conv_w[(e+1)*4 + k];
            acc[2] += bf2f(xv.z) * conv_w[(e+2)*4 + k];
            acc[3] += bf2f(xv.w) * conv_w[(e+3)*4 + k];
        }
    }
    float4 so; ushort4 sb;
    float* sp = (float*)&so;
    #pragma unroll
    for (int j = 0; j < 4; ++j){
        float s = acc[j] / (1.f + __expf(-acc[j]));
        sp[j] = s;
    }
    sb.x = f2bf(so.x); sb.y = f2bf(so.y); sb.z = f2bf(so.z); sb.w = f2bf(so.w);
    *(float4*)(xf + idx) = so;
    *(ushort4*)(xb + idx) = sb;
}

// ---------------- chunk-parallel selective scan, delta fused via MFMA ----------------
// delta[t,e] = softplus(dot64(xr[t,:], wd2[e,:]) + wd2_b[e]); xr = C96 cols 0..63.
// Pass 1 (seg1): local scan from 0 -> F, segdt. Pass 2 (carry_k). Pass 3 (seg2): y.
#define SLDF 68   // float tile stride (272B, 16B-aligned)
#define SLDH 72   // ushort tile stride (144B, 16B-aligned)

// grid (E_/16, SSEG, B_), block 256 = 16 e x 16 n
__global__ __launch_bounds__(256) void seg1_k(const float* __restrict__ xf,
                                              const ushort* __restrict__ C96,
                                              const ushort* __restrict__ wd2b,
                                              const float* __restrict__ wd2_bias,
                                              const float* __restrict__ A_log,
                                              float* __restrict__ F,
                                              float* __restrict__ segdt){
    const int b = blockIdx.z, s = blockIdx.y, e0 = blockIdx.x * 16;
    const int tid = threadIdx.x;
    const int lane = tid & 63, wid = tid >> 6;
    const int n = tid & 15, ei = tid >> 4;
    const int e = e0 + ei;
    const float Aen = -__expf(A_log[e * N_ + n]);
    float h = 0.f, sdt = 0.f;
    __shared__ __align__(16) ushort sxr[64][SLDH];
    __shared__ __align__(16) ushort swd2[16][SLDH];
    __shared__ float sd[16][SLDF], sx[16][SLDF], sB[16][SLDF];
    const int tq = tid >> 2, qc = tid & 3;

    if (tid < 128){
        int r = tid >> 3, cc = (tid & 7) * 8;
        *(uint4*)&swd2[r][cc] = *(const uint4*)(wd2b + (size_t)(e0 + r) * DR_ + cc);
    }
    const float bias = wd2_bias[e0 + (lane & 15)];

    for (int c = 0; c < LSEG / 64; ++c){
        int t0 = s * LSEG + c * 64;
        size_t row = (size_t)(b * L_ + t0 + tq);
        *(uint4*)&sxr[tq][qc * 16]     = *(const uint4*)(C96 + row * 128 + qc * 16);
        *(uint4*)&sxr[tq][qc * 16 + 8] = *(const uint4*)(C96 + row * 128 + qc * 16 + 8);
        ushort4 rB = *(const ushort4*)(C96 + row * 128 + 64 + qc * 4);
        float4  rx = *(const float4*)(xf + row * E_ + e0 + qc * 4);
        sB[qc*4+0][tq] = bf2f(rB.x); sB[qc*4+1][tq] = bf2f(rB.y);
        sB[qc*4+2][tq] = bf2f(rB.z); sB[qc*4+3][tq] = bf2f(rB.w);
        sx[qc*4+0][tq] = rx.x; sx[qc*4+1][tq] = rx.y;
        sx[qc*4+2][tq] = rx.z; sx[qc*4+3][tq] = rx.w;
        __syncthreads();
        // fused delta: wave wid computes t rows wid*16..+15 x 16 e's
        f32x4 dacc = {};
        #pragma unroll
        for (int kk = 0; kk < 2; ++kk){
            bf16x8 af = *(const bf16x8*)&sxr[wid*16 + (lane & 15)][kk*32 + (lane >> 4)*8];
            bf16x8 bf = *(const bf16x8*)&swd2[lane & 15][kk*32 + (lane >> 4)*8];
            dacc = __builtin_amdgcn_mfma_f32_16x16x32_bf16(af, bf, dacc, 0, 0, 0);
        }
        #pragma unroll
        for (int j = 0; j < 4; ++j){
            int tt = wid*16 + (lane >> 4)*4 + j;
            float z = dacc[j] + bias;
            sd[lane & 15][tt] = (z > 20.f) ? z : log1pf(__expf(z));
        }
        __syncthreads();
        #pragma unroll
        for (int t = 0; t < 64; t += 4){
            float4 d4 = *(const float4*)&sd[ei][t];
            float4 x4 = *(const float4*)&sx[ei][t];
            float4 b4 = *(const float4*)&sB[n][t];
            h = __expf(d4.x*Aen)*h + d4.x*x4.x*b4.x;
            h = __expf(d4.y*Aen)*h + d4.y*x4.y*b4.y;
            h = __expf(d4.z*Aen)*h + d4.z*x4.z*b4.z;
            h = __expf(d4.w*Aen)*h + d4.w*x4.w*b4.w;
            sdt += d4.x + d4.y + d4.z + d4.w;
        }
        __syncthreads();
    }
    size_t base = ((size_t)(b * SSEG + s) * E_ + e) * N_ + n;
    F[base] = h;
    if (n == 0) segdt[(size_t)(b * SSEG + s) * E_ + e] = sdt;
}

// sequential carry over SSEG segments per (b,e,n)
__global__ __launch_bounds__(256) void carry_k(const float* __restrict__ F,
                                               const float* __restrict__ segdt,
                                               const float* __restrict__ A_log,
                                               float* __restrict__ carr){
    int idx = blockIdx.x * 256 + threadIdx.x;
    int n = idx & 15;
    int e = (idx >> 4) & (E_ - 1);
    int b = idx >> 15;
    const float Aen = -__expf(A_log[e * N_ + n]);
    float c = 0.f;
    #pragma unroll
    for (int s = 0; s < SSEG; ++s){
        size_t base = ((size_t)(b * SSEG + s) * E_ + e) * N_ + n;
        carr[base] = c;
        float P = __expf(Aen * segdt[(size_t)(b * SSEG + s) * E_ + e]);
        c = P * c + F[base];
    }
}

// grid (E_/16, SSEG, B_), block 256
__global__ __launch_bounds__(256) void seg2_k(const float* __restrict__ xf,
                                              const ushort* __restrict__ C96,
                                              const ushort* __restrict__ wd2b,
                                              const float* __restrict__ wd2_bias,
                                              const float* __restrict__ A_log,
                                              const float* __restrict__ carr,
                                              float* __restrict__ ys){
    const int b = blockIdx.z, s = blockIdx.y, e0 = blockIdx.x * 16;
    const int tid = threadIdx.x;
    const int lane = tid & 63, wid = tid >> 6;
    const int n = tid & 15, ei = tid >> 4;
    const int e = e0 + ei;
    const float Aen = -__expf(A_log[e * N_ + n]);
    float h = carr[((size_t)(b * SSEG + s) * E_ + e) * N_ + n];
    __shared__ __align__(16) ushort sxr[64][SLDH];
    __shared__ __align__(16) ushort swd2[16][SLDH];
    __shared__ float sd[16][SLDF], sx[16][SLDF], sB[16][SLDF], sC[16][SLDF];
    __shared__ float sy[64][16];
    const int tq = tid >> 2, qc = tid & 3;

    if (tid < 128){
        int r = tid >> 3, cc = (tid & 7) * 8;
        *(uint4*)&swd2[r][cc] = *(const uint4*)(wd2b + (size_t)(e0 + r) * DR_ + cc);
    }
    const float bias = wd2_bias[e0 + (lane & 15)];

    for (int c = 0; c < LSEG / 64; ++c){
        int t0 = s * LSEG + c * 64;
        size_t row = (size_t)(b * L_ + t0 + tq);
        *(uint4*)&sxr[tq][qc * 16]     = *(const uint4*)(C96 + row * 128 + qc * 16);
        *(uint4*)&sxr[tq][qc * 16 + 8] = *(const uint4*)(C96 + row * 128 + qc * 16 + 8);
        ushort4 rB = *(const ushort4*)(C96 + row * 128 + 64 + qc * 4);
        ushort4 rC = *(const ushort4*)(C96 + row * 128 + 80 + qc * 4);
        float4  rx = *(const float4*)(xf + row * E_ + e0 + qc * 4);
        sB[qc*4+0][tq] = bf2f(rB.x); sB[qc*4+1][tq] = bf2f(rB.y);
        sB[qc*4+2][tq] = bf2f(rB.z); sB[qc*4+3][tq] = bf2f(rB.w);
        sC[qc*4+0][tq] = bf2f(rC.x); sC[qc*4+1][tq] = bf2f(rC.y);
        sC[qc*4+2][tq] = bf2f(rC.z); sC[qc*4+3][tq] = bf2f(rC.w);
        sx[qc*4+0][tq] = rx.x; sx[qc*4+1][tq] = rx.y;
        sx[qc*4+2][tq] = rx.z; sx[qc*4+3][tq] = rx.w;
        __syncthreads();
        f32x4 dacc = {};
        #pragma unroll
        for (int kk = 0; kk < 2; ++kk){
            bf16x8 af = *(const bf16x8*)&sxr[wid*16 + (lane & 15)][kk*32 + (lane >> 4)*8];
            bf16x8 bf = *(const bf16x8*)&swd2[lane & 15][kk*32 + (lane >> 4)*8];
            dacc = __builtin_amdgcn_mfma_f32_16x16x32_bf16(af, bf, dacc, 0, 0, 0);
        }
        #pragma unroll
        for (int j = 0; j < 4; ++j){
            int tt = wid*16 + (lane >> 4)*4 + j;
            float z = dacc[j] + bias;
            sd[lane & 15][tt] = (z > 20.f) ? z : log1pf(__expf(z));
        }
        __syncthreads();
        #pragma unroll
        for (int t = 0; t < 64; t += 4){
            float4 d4 = *(const float4*)&sd[ei][t];
            float4 x4 = *(const float4*)&sx[ei][t];
            float4 b4 = *(const float4*)&sB[n][t];
            float4 c4 = *(const float4*)&sC[n][t];
            float y0, y1, y2, y3;
            h = __expf(d4.x*Aen)*h + d4.x*x4.x*b4.x;  y0 = h * c4.x;
            h = __expf(d4.y*Aen)*h + d4.y*x4.y*b4.y;  y1 = h * c4.y;
            h = __expf(d4.z*Aen)*h + d4.z*x4.z*b4.z;  y2 = h * c4.z;
            h = __expf(d4.w*Aen)*h + d4.w*x4.w*b4.w;  y3 = h * c4.w;
            // 4-value 16-lane butterfly reduce: 5 shfls
            float s01 = (n & 1) ? y0 : y1;
            float r01 = __shfl_xor(s01, 1);
            float s23 = (n & 1) ? y2 : y3;
            float r23 = __shfl_xor(s23, 1);
            float va, vb;
            if (n & 1){ va = y1 + r01; vb = y3 + r23; }
            else      { va = y0 + r01; vb = y2 + r23; }
            float s2 = (n & 2) ? va : vb;
            float r2 = __shfl_xor(s2, 2);
            float v = ((n & 2) ? vb : va) + r2;
            v += __shfl_xor(v, 4);
            v += __shfl_xor(v, 8);
            if (n < 4) sy[t + n][ei] = v;
        }
        __syncthreads();
        {
            size_t orow = (size_t)(b * L_ + t0 + tq);
            *(float4*)(ys + orow * E_ + e0 + qc * 4) = *(float4*)&sy[tq][qc * 4];
        }
        __syncthreads();
    }
}

// ---------------- gating: y2 = (ys + W_D*x) * silu(skip) -> bf16 (vec4) ----------------
__global__ __launch_bounds__(256) void gate_k(const float* __restrict__ ys,
                                              const float* __restrict__ xf,
                                              const ushort* __restrict__ skipb,
                                              const float* __restrict__ W_D,
                                              ushort* __restrict__ y2){
    int i4 = blockIdx.x * 256 + threadIdx.x;
    if (i4 >= M_ * E_ / 4) return;
    int idx = i4 * 4;
    int e = idx & (E_ - 1);
    float4 yv = *(const float4*)(ys + idx);
    float4 xv = *(const float4*)(xf + idx);
    ushort4 sv = *(const ushort4*)(skipb + idx);
    float4 wv = *(const float4*)(W_D + e);
    float sk0 = bf2f(sv.x), sk1 = bf2f(sv.y), sk2 = bf2f(sv.z), sk3 = bf2f(sv.w);
    ushort4 o;
    o.x = f2bf((yv.x + wv.x * xv.x) * (sk0 / (1.f + __expf(-sk0))));
    o.y = f2bf((yv.y + wv.y * xv.y) * (sk1 / (1.f + __expf(-sk1))));
    o.z = f2bf((yv.z + wv.z * xv.z) * (sk2 / (1.f + __expf(-sk2))));
    o.w = f2bf((yv.w + wv.w * xv.w) * (sk3 / (1.f + __expf(-sk3))));
    *(ushort4*)(y2 + idx) = o;
}

// ---------------- launch ----------------
extern "C" void kernel_launch(void* const* d_in, const int* in_sizes, int n_in,
                              void* d_out, int out_size, void* d_ws, size_t ws_size,
                              hipStream_t stream){
    const float* resid  = (const float*)d_in[0];
    const float* norm_w = (const float*)d_in[1];
    const float* skip_w = (const float*)d_in[2];
    const float* in_w   = (const float*)d_in[3];
    const float* conv_w = (const float*)d_in[4];
    const float* conv_b = (const float*)d_in[5];
    const float* wd1    = (const float*)d_in[6];
    const float* wd2    = (const float*)d_in[7];
    const float* wd2_b  = (const float*)d_in[8];
    const float* wB     = (const float*)d_in[9];
    const float* wC     = (const float*)d_in[10];
    const float* A_log  = (const float*)d_in[11];
    const float* W_D    = (const float*)d_in[12];
    const float* out_w  = (const float*)d_in[13];
    float* out = (float*)d_out;

    char* ws = (char*)d_ws;
    size_t off = 0;
    auto alloc = [&](size_t bytes) -> char* {
        char* p = ws + off;
        off += (bytes + 255) & ~(size_t)255;
        return p;
    };
    // --- aliased region: wi, wsk, xn (16MB) are dead before the C96 GEMM runs;
    //     split-K partial buffer (16MB f32) reuses them.
    char* alias_base = ws;
    ushort* wi_b    = (ushort*)alloc((size_t)E_ * D_ * 2);   // 4MB
    ushort* wsk_b   = (ushort*)alloc((size_t)E_ * D_ * 2);   // 4MB
    ushort* xn_b    = (ushort*)alloc((size_t)M_ * D_ * 2);   // 8MB
    ushort* xpre_b  = (ushort*)alloc((size_t)M_ * E_ * 2);   // 16MB
    float*  part_buf= (float*)alias_base;                    // 16MB alias (KS_*M_*128*4)
    // --- persistent buffers
    ushort* wo_b    = (ushort*)alloc((size_t)D_ * E_ * 2);       // 4MB
    ushort* wd2_bf  = (ushort*)alloc((size_t)E_ * DR_ * 2);      // 256KB
    ushort* W96_b   = (ushort*)alloc((size_t)128 * E_ * 2);      // 512KB
    ushort* skip_b  = (ushort*)alloc((size_t)M_ * E_ * 2);       // 16MB
    float*  xff     = (float*)alloc((size_t)M_ * E_ * 4);        // 32MB
    ushort* xb_b    = (ushort*)alloc((size_t)M_ * E_ * 2);       // 16MB
    ushort* C96_b   = (ushort*)alloc((size_t)M_ * 128 * 2);      // 1MB
    float*  ysf     = (float*)alloc((size_t)M_ * E_ * 4);        // 32MB
    ushort* y2_b    = (ushort*)alloc((size_t)M_ * E_ * 2);       // 16MB
    // --- scan scratch aliases y2_b region (dead until gate_k)
    float* F_buf    = (float*)y2_b;
    float* carr_buf = (float*)((char*)y2_b + (size_t)B_ * SSEG * E_ * N_ * 4);
    float* segdt_buf= (float*)((char*)y2_b + (size_t)2 * B_ * SSEG * E_ * N_ * 4);
    (void)ws_size; (void)in_sizes; (void)n_in; (void)out_size;

    const int thr = 256;
    auto blocks4 = [](int n){ return (n/4 + 255) / 256; };

    // weight conversions
    cvt4_k<<<blocks4(E_*D_), thr, 0, stream>>>(in_w,   wi_b,   E_*D_/4);
    cvt4_k<<<blocks4(E_*D_), thr, 0, stream>>>(skip_w, wsk_b,  E_*D_/4);
    cvt4_k<<<blocks4(D_*E_), thr, 0, stream>>>(out_w,  wo_b,   D_*E_/4);
    cvt4_k<<<blocks4(E_*DR_), thr, 0, stream>>>(wd2,   wd2_bf, E_*DR_/4);
    cvt4_k<<<blocks4(DR_*E_), thr, 0, stream>>>(wd1,   W96_b,            DR_*E_/4);
    cvt4_k<<<blocks4(N_*E_),  thr, 0, stream>>>(wB,    W96_b + 64*E_,    N_*E_/4);
    cvt4_k<<<blocks4(N_*E_),  thr, 0, stream>>>(wC,    W96_b + 80*E_,    N_*E_/4);
    zero16_k<<<(32*E_ + 255)/256, thr, 0, stream>>>(W96_b + 96*E_, 32*E_);

    // RMSNorm
    rmsnorm_k<<<M_, thr, 0, stream>>>(resid, norm_w, xn_b);

    // in-proj and skip-proj GEMMs: [4096,2048] = [4096,1024] x [2048,1024]^T
    gemm_bt<1><<<dim3(E_/BN, M_/BM), thr, 0, stream>>>(xn_b, wi_b,  xpre_b, nullptr, M_, E_, D_, D_, D_, E_);
    gemm_bt<1><<<dim3(E_/BN, M_/BM), thr, 0, stream>>>(xn_b, wsk_b, skip_b, nullptr, M_, E_, D_, D_, D_, E_);

    // conv + silu
    conv_silu_k<<<(M_*E_/4 + 255)/256, thr, 0, stream>>>(xpre_b, conv_w, conv_b, xff, xb_b);

    // C96[4096,128] = x[4096,2048] x W96[128,2048]^T, split-K x8 + reduce
    gemm_c96_sk<<<dim3(KS_, M_/BM), thr, 0, stream>>>(xb_b, W96_b, part_buf);
    c96_reduce_k<<<(M_*128/4)/256, thr, 0, stream>>>(part_buf, C96_b);

    // chunk-parallel selective scan with fused delta
    seg1_k<<<dim3(E_/16, SSEG, B_), thr, 0, stream>>>(xff, C96_b, wd2_bf, wd2_b, A_log, F_buf, segdt_buf);
    carry_k<<<(B_*E_*N_)/256, thr, 0, stream>>>(F_buf, segdt_buf, A_log, carr_buf);
    seg2_k<<<dim3(E_/16, SSEG, B_), thr, 0, stream>>>(xff, C96_b, wd2_bf, wd2_b, A_log, carr_buf, ysf);

    // gating
    gate_k<<<(M_*E_/4 + 255)/256, thr, 0, stream>>>(ysf, xff, skip_b, W_D, y2_b);

    // out-proj + residual: out[4096,1024] = y2[4096,2048] x out_w[1024,2048]^T + resid
    gemm_bt<3><<<dim3(D_/BN, M_/BM), thr, 0, stream>>>(y2_b, wo_b, out, resid, M_, D_, E_, E_, E_, D_);
}